// Round 15
// baseline (230.143 us; speedup 1.0000x reference)
//
#include <hip/hip_runtime.h>
#include <stdint.h>

#define DEV __device__ __forceinline__

typedef __attribute__((ext_vector_type(8))) short bf16x8_t;   // 8 bf16 in 4 VGPRs
typedef __attribute__((ext_vector_type(4))) float f32x4_t;

DEV unsigned short f2bf(float f) {
  union { float f; uint32_t u; } x; x.f = f;
  uint32_t r = x.u + 0x7fffu + ((x.u >> 16) & 1u);
  return (unsigned short)(r >> 16);
}
DEV float bf2f(unsigned short u) {
  union { uint32_t u; float f; } x; x.u = ((uint32_t)u) << 16;
  return x.f;
}

#define GLOAD_LDS16(g, l)                                                              \
  __builtin_amdgcn_global_load_lds((const __attribute__((address_space(1))) unsigned int*)(g), \
                                   (__attribute__((address_space(3))) unsigned int*)(l), 16, 0, 0)

// ---------------- one-time gather: Wdt[h][k] = W_in[k][2176+h] ----------------
__global__ __launch_bounds__(256) void wdt_kernel(const float* __restrict__ W_in, float* __restrict__ Wdt) {
  int k = blockIdx.x * 256 + threadIdx.x;
  if (k < 1024) {
#pragma unroll
    for (int h = 0; h < 8; ++h)
      Wdt[h * 1024 + k] = W_in[(size_t)k * 2184 + 2176 + h];
  }
}

// ---------------- fused: u -> bf16 copy + dt = softplus(u @ Wdt^T + dt_bias), 4 rows/block ----------------
__global__ __launch_bounds__(256) void uin_kernel(const float* __restrict__ u, const float* __restrict__ Wdt,
                                                  const float* __restrict__ dt_bias,
                                                  unsigned short* __restrict__ A1, float* __restrict__ dtv) {
  int tid = threadIdx.x;
  int row0 = blockIdx.x * 4;
  int lane = tid & 63, wv = tid >> 6;
  float4 w4[8];
#pragma unroll
  for (int h = 0; h < 8; ++h) w4[h] = reinterpret_cast<const float4*>(Wdt + h * 1024)[tid];
  __shared__ float red[4][8];
#pragma unroll
  for (int r = 0; r < 4; ++r) {
    int row = row0 + r;
    float4 v = reinterpret_cast<const float4*>(u + (size_t)row * 1024)[tid];
    ushort4 o;
    o.x = f2bf(v.x); o.y = f2bf(v.y); o.z = f2bf(v.z); o.w = f2bf(v.w);
    reinterpret_cast<ushort4*>(A1 + (size_t)row * 1024)[tid] = o;
    float ps[8];
#pragma unroll
    for (int h = 0; h < 8; ++h)
      ps[h] = v.x * w4[h].x + v.y * w4[h].y + v.z * w4[h].z + v.w * w4[h].w;
#pragma unroll
    for (int h = 0; h < 8; ++h)
#pragma unroll
      for (int off = 32; off > 0; off >>= 1) ps[h] += __shfl_down(ps[h], off, 64);
    if (lane == 0) {
#pragma unroll
      for (int h = 0; h < 8; ++h) red[wv][h] = ps[h];
    }
    __syncthreads();
    if (tid < 8) {
      float s = red[0][tid] + red[1][tid] + red[2][tid] + red[3][tid] + dt_bias[tid];
      float sp = (s > 20.f) ? s : log1pf(expf(s));
      dtv[(size_t)row * 8 + tid] = sp;
    }
    __syncthreads();
  }
}

// ---------------- transpose fp32 (R x Cin, row stride) -> bf16 (C x R), zero-pad ----------------
__global__ void transpose_bf16_kernel(const float* __restrict__ in, unsigned short* __restrict__ out,
                                      int R, int Cin, int stride) {
  __shared__ float t[32][33];
  int bx = blockIdx.x, by = blockIdx.y;
  int tx = threadIdx.x, ty = threadIdx.y;
#pragma unroll
  for (int q = 0; q < 4; ++q) {
    int r = by * 32 + ty + q * 8, c = bx * 32 + tx;
    t[ty + q * 8][tx] = (c < Cin) ? in[(size_t)r * stride + c] : 0.f;
  }
  __syncthreads();
#pragma unroll
  for (int q = 0; q < 4; ++q) {
    int oc = bx * 32 + ty + q * 8;
    int orr = by * 32 + tx;
    out[(size_t)oc * R + orr] = f2bf(t[tx][ty + q * 8]);
  }
}

// ======== 128x256 MFMA GEMM, BK=32, counted-vmcnt TRIPLE buffer, 8 waves, 72KB LDS ========
template <int OBF>
__global__ __launch_bounds__(512) void gemm_tb_kernel(const unsigned short* __restrict__ A,
                                                      const unsigned short* __restrict__ Bt,
                                                      void* __restrict__ Cout, int K, int ldc, int gx) {
  __shared__ __align__(16) char lds[3 * 24576];
  int tid = threadIdx.x, lane = tid & 63, wv = tid >> 6;
  int lr = lane & 15, lk = lane >> 4;
  int wm = wv >> 2, wn = wv & 3;

  int nwg = gridDim.x, lin = blockIdx.x, wg = lin;
  if ((nwg & 7) == 0) { int cpx = nwg >> 3; wg = (lin & 7) * cpx + (lin >> 3); }
  long tileM = (long)(wg % gx) * 128;
  long tileN = (long)(wg / gx) * 256;

  const unsigned short* gAp;
  {
    int q = tid, row = q >> 2, c = (q & 3) ^ ((row >> 1) & 3);
    gAp = A + (size_t)(tileM + row) * K + c * 8;
  }
  const unsigned short* gBp[2];
#pragma unroll
  for (int i = 0; i < 2; ++i) {
    int q = tid + i * 512, row = q >> 2, c = (q & 3) ^ ((row >> 1) & 3);
    gBp[i] = Bt + (size_t)(tileN + row) * K + c * 8;
  }

#define STAGE_TB(bsel, kof)                                                                  \
  do {                                                                                       \
    GLOAD_LDS16(gAp + (kof), lds + (bsel) * 24576 + tid * 16);                               \
    _Pragma("unroll") for (int i_ = 0; i_ < 2; ++i_)                                         \
        GLOAD_LDS16(gBp[i_] + (kof), lds + (bsel) * 24576 + 8192 + (tid + i_ * 512) * 16);   \
  } while (0)

  f32x4_t acc[4][4];
#pragma unroll
  for (int i = 0; i < 4; ++i)
#pragma unroll
    for (int j = 0; j < 4; ++j) acc[i][j] = f32x4_t{0.f, 0.f, 0.f, 0.f};

  int NT = K >> 5;
  STAGE_TB(0, 0);
  STAGE_TB(1, 32);

  int colsw = ((lk ^ ((lr >> 1) & 3)) << 4);
  int rsel = 0, wsel = 2;
  for (int t = 0; t < NT; ++t) {
    __builtin_amdgcn_s_barrier();
    if (t + 2 < NT) {
      STAGE_TB(wsel, (t + 2) * 32);
      asm volatile("s_waitcnt vmcnt(6)" ::: "memory");
    } else if (t + 1 < NT) {
      asm volatile("s_waitcnt vmcnt(3)" ::: "memory");
    } else {
      asm volatile("s_waitcnt vmcnt(0)" ::: "memory");
    }
    __builtin_amdgcn_s_barrier();

    const char* base = lds + rsel * 24576;
    bf16x8_t a[4], b[4];
#pragma unroll
    for (int mf = 0; mf < 4; ++mf)
      a[mf] = *reinterpret_cast<const bf16x8_t*>(base + (wm * 64 + mf * 16 + lr) * 64 + colsw);
#pragma unroll
    for (int nf = 0; nf < 4; ++nf)
      b[nf] = *reinterpret_cast<const bf16x8_t*>(base + 8192 + (wn * 64 + nf * 16 + lr) * 64 + colsw);
    __builtin_amdgcn_s_setprio(1);
#pragma unroll
    for (int mf = 0; mf < 4; ++mf)
#pragma unroll
      for (int nf = 0; nf < 4; ++nf)
        acc[mf][nf] = __builtin_amdgcn_mfma_f32_16x16x32_bf16(a[mf], b[nf], acc[mf][nf], 0, 0, 0);
    __builtin_amdgcn_s_setprio(0);
    rsel = (rsel == 2) ? 0 : rsel + 1;
    wsel = (wsel == 2) ? 0 : wsel + 1;
  }
#undef STAGE_TB

#pragma unroll
  for (int mf = 0; mf < 4; ++mf)
#pragma unroll
    for (int nf = 0; nf < 4; ++nf) {
      long r0 = tileM + wm * 64 + mf * 16 + lk * 4;
      long c0 = tileN + wn * 64 + nf * 16 + lr;
#pragma unroll
      for (int r = 0; r < 4; ++r) {
        if (OBF)
          ((unsigned short*)Cout)[(size_t)(r0 + r) * ldc + c0] = f2bf(acc[mf][nf][r]);
        else
          ((float*)Cout)[(size_t)(r0 + r) * ldc + c0] = acc[mf][nf][r];
      }
    }
}

// ======== 128x128 MFMA GEMM, BK=32, counted-vmcnt TRIPLE buffer, 4 waves, 48KB LDS ========
// For GEMM2 (N=1024): grid 512 blocks, 2-3 blocks/CU co-resident, B-panel L2-resident.
template <int OBF>
__global__ __launch_bounds__(256) void gemm_tb128_kernel(const unsigned short* __restrict__ A,
                                                         const unsigned short* __restrict__ Bt,
                                                         void* __restrict__ Cout, int K, int ldc, int gx) {
  __shared__ __align__(16) char lds[3 * 16384];
  int tid = threadIdx.x, lane = tid & 63, wv = tid >> 6;
  int lr = lane & 15, lk = lane >> 4;
  int wm = wv >> 1, wn = wv & 1;

  int nwg = gridDim.x, lin = blockIdx.x, wg = lin;
  if ((nwg & 7) == 0) { int cpx = nwg >> 3; wg = (lin & 7) * cpx + (lin >> 3); }
  long tileM = (long)(wg % gx) * 128;
  long tileN = (long)(wg / gx) * 128;

  const unsigned short* gAp[2];
  const unsigned short* gBp[2];
#pragma unroll
  for (int i = 0; i < 2; ++i) {
    int q = tid + i * 256, row = q >> 2, c = (q & 3) ^ ((row >> 1) & 3);
    gAp[i] = A + (size_t)(tileM + row) * K + c * 8;
    gBp[i] = Bt + (size_t)(tileN + row) * K + c * 8;
  }

#define STAGE_T128(bsel, kof)                                                                \
  do {                                                                                       \
    _Pragma("unroll") for (int i_ = 0; i_ < 2; ++i_) {                                       \
      GLOAD_LDS16(gAp[i_] + (kof), lds + (bsel) * 16384 + (tid + i_ * 256) * 16);            \
      GLOAD_LDS16(gBp[i_] + (kof), lds + (bsel) * 16384 + 8192 + (tid + i_ * 256) * 16);     \
    }                                                                                        \
  } while (0)

  f32x4_t acc[4][4];
#pragma unroll
  for (int i = 0; i < 4; ++i)
#pragma unroll
    for (int j = 0; j < 4; ++j) acc[i][j] = f32x4_t{0.f, 0.f, 0.f, 0.f};

  int NT = K >> 5;
  STAGE_T128(0, 0);
  STAGE_T128(1, 32);

  int colsw = ((lk ^ ((lr >> 1) & 3)) << 4);
  int rsel = 0, wsel = 2;
  for (int t = 0; t < NT; ++t) {
    __builtin_amdgcn_s_barrier();
    if (t + 2 < NT) {
      STAGE_T128(wsel, (t + 2) * 32);
      asm volatile("s_waitcnt vmcnt(8)" ::: "memory");
    } else if (t + 1 < NT) {
      asm volatile("s_waitcnt vmcnt(4)" ::: "memory");
    } else {
      asm volatile("s_waitcnt vmcnt(0)" ::: "memory");
    }
    __builtin_amdgcn_s_barrier();

    const char* base = lds + rsel * 16384;
    bf16x8_t a[4], b[4];
#pragma unroll
    for (int mf = 0; mf < 4; ++mf)
      a[mf] = *reinterpret_cast<const bf16x8_t*>(base + (wm * 64 + mf * 16 + lr) * 64 + colsw);
#pragma unroll
    for (int nf = 0; nf < 4; ++nf)
      b[nf] = *reinterpret_cast<const bf16x8_t*>(base + 8192 + (wn * 64 + nf * 16 + lr) * 64 + colsw);
    __builtin_amdgcn_s_setprio(1);
#pragma unroll
    for (int mf = 0; mf < 4; ++mf)
#pragma unroll
      for (int nf = 0; nf < 4; ++nf)
        acc[mf][nf] = __builtin_amdgcn_mfma_f32_16x16x32_bf16(a[mf], b[nf], acc[mf][nf], 0, 0, 0);
    __builtin_amdgcn_s_setprio(0);
    rsel = (rsel == 2) ? 0 : rsel + 1;
    wsel = (wsel == 2) ? 0 : wsel + 1;
  }
#undef STAGE_T128

#pragma unroll
  for (int mf = 0; mf < 4; ++mf)
#pragma unroll
    for (int nf = 0; nf < 4; ++nf) {
      long r0 = tileM + wm * 64 + mf * 16 + lk * 4;
      long c0 = tileN + wn * 64 + nf * 16 + lr;
#pragma unroll
      for (int r = 0; r < 4; ++r) {
        if (OBF)
          ((unsigned short*)Cout)[(size_t)(r0 + r) * ldc + c0] = f2bf(acc[mf][nf][r]);
        else
          ((float*)Cout)[(size_t)(r0 + r) * ldc + c0] = acc[mf][nf][r];
      }
    }
}

// ---------------- causal dwconv(4)+SiLU, register-tiled: 8 t x 8 ch per thread ----------------
template <int C, int IN_STRIDE>
__global__ __launch_bounds__(256) void conv_silu_tile_kernel(const unsigned short* __restrict__ in,
                                                             const float* __restrict__ w,
                                                             const float* __restrict__ bias,
                                                             unsigned short* __restrict__ outp) {
  constexpr int CG = C / 8;
  int idx = blockIdx.x * 256 + threadIdx.x;
  int ch_grp = idx % CG;
  int tb = idx / CG;
  int t0 = (tb & 511) * 8;
  int b = tb >> 9;
  int ch0 = ch_grp * 8;

  float4 wv[8];
#pragma unroll
  for (int e = 0; e < 8; ++e) wv[e] = *reinterpret_cast<const float4*>(w + (ch0 + e) * 4);
  float bs[8];
  {
    float4 b0 = *reinterpret_cast<const float4*>(bias + ch0);
    float4 b1 = *reinterpret_cast<const float4*>(bias + ch0 + 4);
    bs[0] = b0.x; bs[1] = b0.y; bs[2] = b0.z; bs[3] = b0.w;
    bs[4] = b1.x; bs[5] = b1.y; bs[6] = b1.z; bs[7] = b1.w;
  }

  float rows[11][8];
#pragma unroll
  for (int k = 0; k < 11; ++k) {
    int t = t0 - 3 + k;
    if (t >= 0) {
      bf16x8_t v = *reinterpret_cast<const bf16x8_t*>(in + (size_t)((b << 12) + t) * IN_STRIDE + ch0);
#pragma unroll
      for (int e = 0; e < 8; ++e) rows[k][e] = bf2f((unsigned short)v[e]);
    } else {
#pragma unroll
      for (int e = 0; e < 8; ++e) rows[k][e] = 0.f;
    }
  }

#pragma unroll
  for (int tp = 0; tp < 8; ++tp) {
    bf16x8_t o;
#pragma unroll
    for (int e = 0; e < 8; ++e) {
      float a = bs[e] + wv[e].x * rows[tp][e] + wv[e].y * rows[tp + 1][e] +
                wv[e].z * rows[tp + 2][e] + wv[e].w * rows[tp + 3][e];
      a = a / (1.f + expf(-a));
      o[e] = (short)f2bf(a);
    }
    *reinterpret_cast<bf16x8_t*>(outp + (size_t)((b << 12) + t0 + tp) * C + ch0) = o;
  }
}

// ---------------- SSD pass 1 (chunk=64): cumsum + S + Y_diag + chunk states ----------------
__global__ __launch_bounds__(256) void ssd1_kernel(const unsigned short* __restrict__ xBC,
                                                   const float* __restrict__ dtv,
                                                   const float* __restrict__ Alog,
                                                   float* __restrict__ csb,
                                                   unsigned short* __restrict__ stat,
                                                   unsigned short* __restrict__ ypart) {
  int blk = blockIdx.x;
  int h = blk & 7, bc = blk >> 3;
  int c = bc & 63, b = bc >> 6;
  int tid = threadIdx.x, lane = tid & 63, wv = tid >> 6;
  int lr = lane & 15, lk = lane >> 4;
  int base = b * 4096 + c * 64;

  __shared__ float csc[64], dts[64], ew[64];
  __shared__ __align__(16) unsigned short Xd[128 * 72];
  __shared__ __align__(16) unsigned short Bnj[64 * 72];
  __shared__ __align__(16) unsigned short Ss[64 * 72];

  if (wv == 0) {
    int j = lane;
    float dt = dtv[(size_t)(base + j) * 8 + h];
    float A = -expf(Alog[h]);
    float s = dt * A;
#pragma unroll
    for (int off = 1; off < 64; off <<= 1) {
      float v = __shfl_up(s, off, 64);
      if (lane >= off) s += v;
    }
    float csl = __shfl(s, 63, 64);
    csc[j] = s; dts[j] = dt; ew[j] = expf(csl - s);
    csb[(size_t)blk * 64 + j] = s;
  }
  __syncthreads();

#pragma unroll
  for (int rr = 0; rr < 4; ++rr) {
    int j = rr * 16 + (tid >> 4);
    int pc = tid & 15;
    bf16x8_t v = *reinterpret_cast<const bf16x8_t*>(xBC + (size_t)(base + j) * 1152 + h * 128 + pc * 8);
    float dj = dts[j];
    int js = j ^ ((pc & 7) << 3);
#pragma unroll
    for (int e = 0; e < 8; ++e) {
      int p = pc * 8 + e;
      Xd[p * 72 + js] = f2bf(bf2f((unsigned short)v[e]) * dj);
    }
  }
#pragma unroll
  for (int rr = 0; rr < 2; ++rr) {
    int j = rr * 32 + (tid >> 3);
    int nc = tid & 7;
    bf16x8_t v = *reinterpret_cast<const bf16x8_t*>(xBC + (size_t)(base + j) * 1152 + 1024 + nc * 8);
    int js = j ^ ((nc & 7) << 3);
#pragma unroll
    for (int e = 0; e < 8; ++e) {
      int n = nc * 8 + e;
      Bnj[n * 72 + js] = (unsigned short)v[e];
    }
  }

  bf16x8_t cf[2];
  {
    size_t crow = (size_t)(base + wv * 16 + lr) * 1152 + 1088;
    cf[0] = *reinterpret_cast<const bf16x8_t*>(xBC + crow + lk * 8);
    cf[1] = *reinterpret_cast<const bf16x8_t*>(xBC + crow + 32 + lk * 8);
  }
  f32x4_t sacc[4];
#pragma unroll
  for (int jf = 0; jf < 4; ++jf) sacc[jf] = f32x4_t{0.f, 0.f, 0.f, 0.f};
#pragma unroll
  for (int ks = 0; ks < 2; ++ks) {
#pragma unroll
    for (int jf = 0; jf < 4; ++jf) {
      bf16x8_t bv = *reinterpret_cast<const bf16x8_t*>(
          xBC + (size_t)(base + jf * 16 + lr) * 1152 + 1024 + ks * 32 + lk * 8);
      sacc[jf] = __builtin_amdgcn_mfma_f32_16x16x32_bf16(cf[ks], bv, sacc[jf], 0, 0, 0);
    }
  }
  __syncthreads();

  {
    float csi[4];
#pragma unroll
    for (int r = 0; r < 4; ++r) csi[r] = csc[wv * 16 + lk * 4 + r];
#pragma unroll
    for (int jf = 0; jf < 4; ++jf) {
      int j = jf * 16 + lr;
      float csj = csc[j];
#pragma unroll
      for (int r = 0; r < 4; ++r) {
        int i = wv * 16 + lk * 4 + r;
        float w = (j <= i) ? expf(csi[r] - csj) : 0.f;
        Ss[i * 72 + j] = f2bf(sacc[jf][r] * w);
      }
    }
  }
  __syncthreads();

  f32x4_t yacc[8];
#pragma unroll
  for (int pf = 0; pf < 8; ++pf) yacc[pf] = f32x4_t{0.f, 0.f, 0.f, 0.f};
  bf16x8_t sa[2];
  sa[0] = *reinterpret_cast<const bf16x8_t*>(Ss + (wv * 16 + lr) * 72 + lk * 8);
  sa[1] = *reinterpret_cast<const bf16x8_t*>(Ss + (wv * 16 + lr) * 72 + 32 + lk * 8);
#pragma unroll
  for (int ks = 0; ks < 2; ++ks) {
    int jb = ks * 32 + lk * 8;
#pragma unroll
    for (int pf = 0; pf < 8; ++pf) {
      int p = pf * 16 + lr;
      bf16x8_t xv = *reinterpret_cast<const bf16x8_t*>(Xd + p * 72 + (jb ^ (((p >> 3) & 7) << 3)));
      yacc[pf] = __builtin_amdgcn_mfma_f32_16x16x32_bf16(sa[ks], xv, yacc[pf], 0, 0, 0);
    }
  }

  f32x4_t st[2][4];
#pragma unroll
  for (int pb = 0; pb < 2; ++pb)
#pragma unroll
    for (int nf = 0; nf < 4; ++nf) st[pb][nf] = f32x4_t{0.f, 0.f, 0.f, 0.f};
#pragma unroll
  for (int pb = 0; pb < 2; ++pb) {
    int p = wv * 32 + pb * 16 + lr;
#pragma unroll
    for (int ks = 0; ks < 2; ++ks) {
      int jb = ks * 32 + lk * 8;
      bf16x8_t xv = *reinterpret_cast<const bf16x8_t*>(Xd + p * 72 + (jb ^ (((p >> 3) & 7) << 3)));
      bf16x8_t xs;
#pragma unroll
      for (int e = 0; e < 8; ++e) xs[e] = (short)f2bf(bf2f((unsigned short)xv[e]) * ew[jb + e]);
#pragma unroll
      for (int nf = 0; nf < 4; ++nf) {
        int n = nf * 16 + lr;
        bf16x8_t bv = *reinterpret_cast<const bf16x8_t*>(Bnj + n * 72 + (jb ^ (((n >> 3) & 7) << 3)));
        st[pb][nf] = __builtin_amdgcn_mfma_f32_16x16x32_bf16(xs, bv, st[pb][nf], 0, 0, 0);
      }
    }
  }

#pragma unroll
  for (int pf = 0; pf < 8; ++pf)
#pragma unroll
    for (int r = 0; r < 4; ++r) {
      int i = wv * 16 + lk * 4 + r;
      ypart[(size_t)(base + i) * 1024 + h * 128 + pf * 16 + lr] = f2bf(yacc[pf][r]);
    }
  unsigned short* so = stat + (size_t)blk * 8192;
#pragma unroll
  for (int pb = 0; pb < 2; ++pb)
#pragma unroll
    for (int nf = 0; nf < 4; ++nf)
#pragma unroll
      for (int r = 0; r < 4; ++r)
        so[(size_t)(wv * 32 + pb * 16 + lk * 4 + r) * 64 + nf * 16 + lr] = f2bf(st[pb][nf][r]);
}

// ---------------- element-parallel inter-chunk scan (64 chunks), prev -> bf16 ----------------
__global__ __launch_bounds__(256) void scan_kernel(const unsigned short* __restrict__ stat,
                                                   const float* __restrict__ csb,
                                                   unsigned short* __restrict__ prevb) {
  int bh = blockIdx.x >> 5;
  int part = blockIdx.x & 31;
  int h = bh & 7, b = bh >> 3;
  int e = part * 256 + threadIdx.x;
  float carry = 0.f;
  for (int c = 0; c < 64; ++c) {
    size_t blk = (size_t)(b * 64 + c) * 8 + h;
    size_t idx = blk * 8192 + e;
    prevb[idx] = f2bf(carry);
    float dec = expf(csb[blk * 64 + 63]);
    carry = bf2f(stat[idx]) + dec * carry;
  }
}

// ---------------- SSD pass 2: Y = ypart + (C e^cs) @ prev^T + D x ----------------
__global__ __launch_bounds__(256) void ssd2_kernel(const unsigned short* __restrict__ xBC,
                                                   const float* __restrict__ csb,
                                                   const unsigned short* __restrict__ prevb,
                                                   const float* __restrict__ Dp,
                                                   const unsigned short* __restrict__ ypart,
                                                   unsigned short* __restrict__ yb) {
  int blk = blockIdx.x;
  int h = blk & 7, bc = blk >> 3;
  int c = bc & 63, b = bc >> 6;
  int tid = threadIdx.x, lane = tid & 63, wv = tid >> 6;
  int lr = lane & 15, lk = lane >> 4;
  int base = b * 4096 + c * 64;
  __shared__ float csc[64];
  if (tid < 64) csc[tid] = csb[(size_t)blk * 64 + tid];
  __syncthreads();

  float sc = expf(csc[wv * 16 + lr]);
  bf16x8_t ca[2];
  {
    size_t crow = (size_t)(base + wv * 16 + lr) * 1152 + 1088;
#pragma unroll
    for (int ks = 0; ks < 2; ++ks) {
      bf16x8_t v = *reinterpret_cast<const bf16x8_t*>(xBC + crow + ks * 32 + lk * 8);
      bf16x8_t d;
#pragma unroll
      for (int e = 0; e < 8; ++e) d[e] = (short)f2bf(bf2f((unsigned short)v[e]) * sc);
      ca[ks] = d;
    }
  }
  f32x4_t acc[8];
#pragma unroll
  for (int pf = 0; pf < 8; ++pf) acc[pf] = f32x4_t{0.f, 0.f, 0.f, 0.f};
#pragma unroll
  for (int ks = 0; ks < 2; ++ks) {
#pragma unroll
    for (int pf = 0; pf < 8; ++pf) {
      bf16x8_t pv = *reinterpret_cast<const bf16x8_t*>(
          prevb + (size_t)blk * 8192 + (size_t)(pf * 16 + lr) * 64 + ks * 32 + lk * 8);
      acc[pf] = __builtin_amdgcn_mfma_f32_16x16x32_bf16(ca[ks], pv, acc[pf], 0, 0, 0);
    }
  }
  float Dh = Dp[h];
#pragma unroll
  for (int pf = 0; pf < 8; ++pf)
#pragma unroll
    for (int r = 0; r < 4; ++r) {
      int i = wv * 16 + lk * 4 + r;
      size_t row = (size_t)(base + i);
      int p = pf * 16 + lr;
      float xr = bf2f(xBC[row * 1152 + h * 128 + p]);
      float yv = bf2f(ypart[row * 1024 + h * 128 + p]) + acc[pf][r] + Dh * xr;
      yb[row * 1024 + h * 128 + p] = f2bf(yv);
    }
}

// ---------------- RMSNorm over concat(y, z) bf16 -> bf16 ----------------
__global__ __launch_bounds__(256) void rmsnorm_kernel(const unsigned short* __restrict__ y,
                                                      const unsigned short* __restrict__ z,
                                                      const float* __restrict__ nw,
                                                      unsigned short* __restrict__ out) {
  int row = blockIdx.x, tid = threadIdx.x;
  ushort4 ya = reinterpret_cast<const ushort4*>(y + (size_t)row * 1024)[tid];
  ushort4 za = reinterpret_cast<const ushort4*>(z + (size_t)row * 1024)[tid];
  float yf[4] = {bf2f(ya.x), bf2f(ya.y), bf2f(ya.z), bf2f(ya.w)};
  float zf[4] = {bf2f(za.x), bf2f(za.y), bf2f(za.z), bf2f(za.w)};
  float ss = yf[0] * yf[0] + yf[1] * yf[1] + yf[2] * yf[2] + yf[3] * yf[3] +
             zf[0] * zf[0] + zf[1] * zf[1] + zf[2] * zf[2] + zf[3] * zf[3];
#pragma unroll
  for (int off = 32; off > 0; off >>= 1) ss += __shfl_down(ss, off, 64);
  __shared__ float red[4];
  __shared__ float stot;
  int lane = tid & 63, wv = tid >> 6;
  if (lane == 0) red[wv] = ss;
  __syncthreads();
  if (tid == 0) stot = rsqrtf((red[0] + red[1] + red[2] + red[3]) * (1.f / 2048.f) + 1e-5f);
  __syncthreads();
  float s = stot;
  float4 w1 = reinterpret_cast<const float4*>(nw)[tid];
  float4 w2 = reinterpret_cast<const float4*>(nw + 1024)[tid];
  ushort4 o1, o2;
  o1.x = f2bf(yf[0] * s * w1.x); o1.y = f2bf(yf[1] * s * w1.y);
  o1.z = f2bf(yf[2] * s * w1.z); o1.w = f2bf(yf[3] * s * w1.w);
  o2.x = f2bf(zf[0] * s * w2.x); o2.y = f2bf(zf[1] * s * w2.y);
  o2.z = f2bf(zf[2] * s * w2.z); o2.w = f2bf(zf[3] * s * w2.w);
  reinterpret_cast<ushort4*>(out + (size_t)row * 2048)[tid] = o1;
  reinterpret_cast<ushort4*>(out + (size_t)row * 2048 + 1024)[tid] = o2;
}

extern "C" void kernel_launch(void* const* d_in, const int* in_sizes, int n_in,
                              void* d_out, int out_size, void* d_ws, size_t ws_size,
                              hipStream_t stream) {
  const float* u       = (const float*)d_in[0];
  const float* W_in    = (const float*)d_in[1];
  const float* xconv_w = (const float*)d_in[2];
  const float* xconv_b = (const float*)d_in[3];
  const float* zconv_w = (const float*)d_in[4];
  const float* zconv_b = (const float*)d_in[5];
  const float* dt_bias = (const float*)d_in[6];
  const float* Alog    = (const float*)d_in[7];
  const float* Dp      = (const float*)d_in[8];
  const float* norm_w  = (const float*)d_in[9];
  const float* W_out   = (const float*)d_in[10];
  float* out = (float*)d_out;

  char* ws = (char*)d_ws;
  size_t o = 0;
  auto alc = [&](size_t bytes) { void* p = (void*)(ws + o); o = (o + bytes + 255) & ~(size_t)255; return p; };
  char* regA = (char*)alc(16777216);    // A1 (u bf16) -> yb (bf16)
  unsigned short* Wt1    = (unsigned short*)alc(4718592);   // W_in^T padded (2304 x 1024)
  unsigned short* Wt2    = (unsigned short*)alc(4194304);   // W_out^T (1024 x 2048)
  char* regZ = (char*)alc(37748736);    // zx (bf16 8192x2304) -> ypart (bf16, dead after convs)
  float*          dtv    = (float*)alc(262144);
  float*          csb    = (float*)alc(262144);
  unsigned short* xBC    = (unsigned short*)alc(18874368);  // 8192x1152 bf16
  unsigned short* zc     = (unsigned short*)alc(16777216);  // 8192x1024 bf16
  char* regS = (char*)alc(33554432);    // stat (bf16) -> normed (bf16 8192x2048)
  unsigned short* prevb  = (unsigned short*)alc(16777216);
  float*          Wdt    = (float*)alc(32768);              // 8 x 1024 fp32
  (void)ws_size; (void)in_sizes; (void)n_in; (void)out_size;

  unsigned short* A1     = (unsigned short*)regA;
  unsigned short* yb     = (unsigned short*)regA;
  unsigned short* zx     = (unsigned short*)regZ;
  unsigned short* ypart  = (unsigned short*)regZ;   // reuses zx region after convs consume it
  unsigned short* stat   = (unsigned short*)regS;
  unsigned short* normed = (unsigned short*)regS;

  dim3 tb(32, 8);
  wdt_kernel<<<4, 256, 0, stream>>>(W_in, Wdt);
  uin_kernel<<<2048, 256, 0, stream>>>(u, Wdt, dt_bias, A1, dtv);
  transpose_bf16_kernel<<<dim3(72, 32), tb, 0, stream>>>(W_in, Wt1, 1024, 2176, 2184);
  transpose_bf16_kernel<<<dim3(32, 64), tb, 0, stream>>>(W_out, Wt2, 2048, 1024, 1024);
  gemm_tb_kernel<1><<<576, 512, 0, stream>>>(A1, Wt1, (void*)zx, 1024, 2304, 64);
  conv_silu_tile_kernel<1152, 2304><<<576, 256, 0, stream>>>(zx + 1024, xconv_w, xconv_b, xBC);
  conv_silu_tile_kernel<1024, 2304><<<512, 256, 0, stream>>>(zx, zconv_w, zconv_b, zc);
  ssd1_kernel<<<1024, 256, 0, stream>>>(xBC, dtv, Alog, csb, stat, ypart);
  scan_kernel<<<512, 256, 0, stream>>>(stat, csb, prevb);
  ssd2_kernel<<<1024, 256, 0, stream>>>(xBC, csb, prevb, Dp, ypart, yb);
  rmsnorm_kernel<<<8192, 256, 0, stream>>>(yb, zc, norm_w, normed);
  gemm_tb128_kernel<0><<<512, 256, 0, stream>>>(normed, Wt2, (void*)out, 2048, 1024, 64);
}

// Round 16
// 224.602 us; speedup vs baseline: 1.0247x; 1.0247x over previous
//
#include <hip/hip_runtime.h>
#include <stdint.h>

#define DEV __device__ __forceinline__

typedef __attribute__((ext_vector_type(8))) short bf16x8_t;   // 8 bf16 in 4 VGPRs
typedef __attribute__((ext_vector_type(4))) float f32x4_t;

DEV unsigned short f2bf(float f) {
  union { float f; uint32_t u; } x; x.f = f;
  uint32_t r = x.u + 0x7fffu + ((x.u >> 16) & 1u);
  return (unsigned short)(r >> 16);
}
DEV float bf2f(unsigned short u) {
  union { uint32_t u; float f; } x; x.u = ((uint32_t)u) << 16;
  return x.f;
}

#define GLOAD_LDS16(g, l)                                                              \
  __builtin_amdgcn_global_load_lds((const __attribute__((address_space(1))) unsigned int*)(g), \
                                   (__attribute__((address_space(3))) unsigned int*)(l), 16, 0, 0)

// ---------------- one-time gather: Wdt[h][k] = W_in[k][2176+h] ----------------
__global__ __launch_bounds__(256) void wdt_kernel(const float* __restrict__ W_in, float* __restrict__ Wdt) {
  int k = blockIdx.x * 256 + threadIdx.x;
  if (k < 1024) {
#pragma unroll
    for (int h = 0; h < 8; ++h)
      Wdt[h * 1024 + k] = W_in[(size_t)k * 2184 + 2176 + h];
  }
}

// ---------------- fused: u -> bf16 copy + dt = softplus(u @ Wdt^T + dt_bias), 4 rows/block ----------------
__global__ __launch_bounds__(256) void uin_kernel(const float* __restrict__ u, const float* __restrict__ Wdt,
                                                  const float* __restrict__ dt_bias,
                                                  unsigned short* __restrict__ A1, float* __restrict__ dtv) {
  int tid = threadIdx.x;
  int row0 = blockIdx.x * 4;
  int lane = tid & 63, wv = tid >> 6;
  float4 w4[8];
#pragma unroll
  for (int h = 0; h < 8; ++h) w4[h] = reinterpret_cast<const float4*>(Wdt + h * 1024)[tid];
  __shared__ float red[4][8];
#pragma unroll
  for (int r = 0; r < 4; ++r) {
    int row = row0 + r;
    float4 v = reinterpret_cast<const float4*>(u + (size_t)row * 1024)[tid];
    ushort4 o;
    o.x = f2bf(v.x); o.y = f2bf(v.y); o.z = f2bf(v.z); o.w = f2bf(v.w);
    reinterpret_cast<ushort4*>(A1 + (size_t)row * 1024)[tid] = o;
    float ps[8];
#pragma unroll
    for (int h = 0; h < 8; ++h)
      ps[h] = v.x * w4[h].x + v.y * w4[h].y + v.z * w4[h].z + v.w * w4[h].w;
#pragma unroll
    for (int h = 0; h < 8; ++h)
#pragma unroll
      for (int off = 32; off > 0; off >>= 1) ps[h] += __shfl_down(ps[h], off, 64);
    if (lane == 0) {
#pragma unroll
      for (int h = 0; h < 8; ++h) red[wv][h] = ps[h];
    }
    __syncthreads();
    if (tid < 8) {
      float s = red[0][tid] + red[1][tid] + red[2][tid] + red[3][tid] + dt_bias[tid];
      float sp = (s > 20.f) ? s : log1pf(expf(s));
      dtv[(size_t)row * 8 + tid] = sp;
    }
    __syncthreads();
  }
}

// ---------------- transpose fp32 (R x Cin, row stride) -> bf16 (C x R), zero-pad ----------------
__global__ void transpose_bf16_kernel(const float* __restrict__ in, unsigned short* __restrict__ out,
                                      int R, int Cin, int stride) {
  __shared__ float t[32][33];
  int bx = blockIdx.x, by = blockIdx.y;
  int tx = threadIdx.x, ty = threadIdx.y;
#pragma unroll
  for (int q = 0; q < 4; ++q) {
    int r = by * 32 + ty + q * 8, c = bx * 32 + tx;
    t[ty + q * 8][tx] = (c < Cin) ? in[(size_t)r * stride + c] : 0.f;
  }
  __syncthreads();
#pragma unroll
  for (int q = 0; q < 4; ++q) {
    int oc = bx * 32 + ty + q * 8;
    int orr = by * 32 + tx;
    out[(size_t)oc * R + orr] = f2bf(t[tx][ty + q * 8]);
  }
}

// ======== 128x256 MFMA GEMM, BK=32, counted-vmcnt TRIPLE buffer, 8 waves, 72KB LDS ========
template <int OBF>
__global__ __launch_bounds__(512) void gemm_tb_kernel(const unsigned short* __restrict__ A,
                                                      const unsigned short* __restrict__ Bt,
                                                      void* __restrict__ Cout, int K, int ldc, int gx) {
  __shared__ __align__(16) char lds[3 * 24576];
  int tid = threadIdx.x, lane = tid & 63, wv = tid >> 6;
  int lr = lane & 15, lk = lane >> 4;
  int wm = wv >> 2, wn = wv & 3;

  int nwg = gridDim.x, lin = blockIdx.x, wg = lin;
  if ((nwg & 7) == 0) { int cpx = nwg >> 3; wg = (lin & 7) * cpx + (lin >> 3); }
  long tileM = (long)(wg % gx) * 128;
  long tileN = (long)(wg / gx) * 256;

  const unsigned short* gAp;
  {
    int q = tid, row = q >> 2, c = (q & 3) ^ ((row >> 1) & 3);
    gAp = A + (size_t)(tileM + row) * K + c * 8;
  }
  const unsigned short* gBp[2];
#pragma unroll
  for (int i = 0; i < 2; ++i) {
    int q = tid + i * 512, row = q >> 2, c = (q & 3) ^ ((row >> 1) & 3);
    gBp[i] = Bt + (size_t)(tileN + row) * K + c * 8;
  }

#define STAGE_TB(bsel, kof)                                                                  \
  do {                                                                                       \
    GLOAD_LDS16(gAp + (kof), lds + (bsel) * 24576 + tid * 16);                               \
    _Pragma("unroll") for (int i_ = 0; i_ < 2; ++i_)                                         \
        GLOAD_LDS16(gBp[i_] + (kof), lds + (bsel) * 24576 + 8192 + (tid + i_ * 512) * 16);   \
  } while (0)

  f32x4_t acc[4][4];
#pragma unroll
  for (int i = 0; i < 4; ++i)
#pragma unroll
    for (int j = 0; j < 4; ++j) acc[i][j] = f32x4_t{0.f, 0.f, 0.f, 0.f};

  int NT = K >> 5;
  STAGE_TB(0, 0);
  STAGE_TB(1, 32);

  int colsw = ((lk ^ ((lr >> 1) & 3)) << 4);
  int rsel = 0, wsel = 2;
  for (int t = 0; t < NT; ++t) {
    __builtin_amdgcn_s_barrier();
    if (t + 2 < NT) {
      STAGE_TB(wsel, (t + 2) * 32);
      asm volatile("s_waitcnt vmcnt(6)" ::: "memory");
    } else if (t + 1 < NT) {
      asm volatile("s_waitcnt vmcnt(3)" ::: "memory");
    } else {
      asm volatile("s_waitcnt vmcnt(0)" ::: "memory");
    }
    __builtin_amdgcn_s_barrier();

    const char* base = lds + rsel * 24576;
    bf16x8_t a[4], b[4];
#pragma unroll
    for (int mf = 0; mf < 4; ++mf)
      a[mf] = *reinterpret_cast<const bf16x8_t*>(base + (wm * 64 + mf * 16 + lr) * 64 + colsw);
#pragma unroll
    for (int nf = 0; nf < 4; ++nf)
      b[nf] = *reinterpret_cast<const bf16x8_t*>(base + 8192 + (wn * 64 + nf * 16 + lr) * 64 + colsw);
    __builtin_amdgcn_s_setprio(1);
#pragma unroll
    for (int mf = 0; mf < 4; ++mf)
#pragma unroll
      for (int nf = 0; nf < 4; ++nf)
        acc[mf][nf] = __builtin_amdgcn_mfma_f32_16x16x32_bf16(a[mf], b[nf], acc[mf][nf], 0, 0, 0);
    __builtin_amdgcn_s_setprio(0);
    rsel = (rsel == 2) ? 0 : rsel + 1;
    wsel = (wsel == 2) ? 0 : wsel + 1;
  }
#undef STAGE_TB

#pragma unroll
  for (int mf = 0; mf < 4; ++mf)
#pragma unroll
    for (int nf = 0; nf < 4; ++nf) {
      long r0 = tileM + wm * 64 + mf * 16 + lk * 4;
      long c0 = tileN + wn * 64 + nf * 16 + lr;
#pragma unroll
      for (int r = 0; r < 4; ++r) {
        if (OBF)
          ((unsigned short*)Cout)[(size_t)(r0 + r) * ldc + c0] = f2bf(acc[mf][nf][r]);
        else
          ((float*)Cout)[(size_t)(r0 + r) * ldc + c0] = acc[mf][nf][r];
      }
    }
}

// ---------------- causal dwconv(4)+SiLU, register-tiled: 8 t x 8 ch per thread ----------------
template <int C, int IN_STRIDE>
__global__ __launch_bounds__(256) void conv_silu_tile_kernel(const unsigned short* __restrict__ in,
                                                             const float* __restrict__ w,
                                                             const float* __restrict__ bias,
                                                             unsigned short* __restrict__ outp) {
  constexpr int CG = C / 8;
  int idx = blockIdx.x * 256 + threadIdx.x;
  int ch_grp = idx % CG;
  int tb = idx / CG;
  int t0 = (tb & 511) * 8;
  int b = tb >> 9;
  int ch0 = ch_grp * 8;

  float4 wv[8];
#pragma unroll
  for (int e = 0; e < 8; ++e) wv[e] = *reinterpret_cast<const float4*>(w + (ch0 + e) * 4);
  float bs[8];
  {
    float4 b0 = *reinterpret_cast<const float4*>(bias + ch0);
    float4 b1 = *reinterpret_cast<const float4*>(bias + ch0 + 4);
    bs[0] = b0.x; bs[1] = b0.y; bs[2] = b0.z; bs[3] = b0.w;
    bs[4] = b1.x; bs[5] = b1.y; bs[6] = b1.z; bs[7] = b1.w;
  }

  float rows[11][8];
#pragma unroll
  for (int k = 0; k < 11; ++k) {
    int t = t0 - 3 + k;
    if (t >= 0) {
      bf16x8_t v = *reinterpret_cast<const bf16x8_t*>(in + (size_t)((b << 12) + t) * IN_STRIDE + ch0);
#pragma unroll
      for (int e = 0; e < 8; ++e) rows[k][e] = bf2f((unsigned short)v[e]);
    } else {
#pragma unroll
      for (int e = 0; e < 8; ++e) rows[k][e] = 0.f;
    }
  }

#pragma unroll
  for (int tp = 0; tp < 8; ++tp) {
    bf16x8_t o;
#pragma unroll
    for (int e = 0; e < 8; ++e) {
      float a = bs[e] + wv[e].x * rows[tp][e] + wv[e].y * rows[tp + 1][e] +
                wv[e].z * rows[tp + 2][e] + wv[e].w * rows[tp + 3][e];
      a = a / (1.f + expf(-a));
      o[e] = (short)f2bf(a);
    }
    *reinterpret_cast<bf16x8_t*>(outp + (size_t)((b << 12) + t0 + tp) * C + ch0) = o;
  }
}

// ---------------- SSD pass 1 (chunk=64): cumsum + S + Y_diag + chunk states ----------------
__global__ __launch_bounds__(256) void ssd1_kernel(const unsigned short* __restrict__ xBC,
                                                   const float* __restrict__ dtv,
                                                   const float* __restrict__ Alog,
                                                   float* __restrict__ csb,
                                                   unsigned short* __restrict__ stat,
                                                   unsigned short* __restrict__ ypart) {
  int blk = blockIdx.x;
  int h = blk & 7, bc = blk >> 3;
  int c = bc & 63, b = bc >> 6;
  int tid = threadIdx.x, lane = tid & 63, wv = tid >> 6;
  int lr = lane & 15, lk = lane >> 4;
  int base = b * 4096 + c * 64;

  __shared__ float csc[64], dts[64], ew[64];
  __shared__ __align__(16) unsigned short Xd[128 * 72];
  __shared__ __align__(16) unsigned short Bnj[64 * 72];
  __shared__ __align__(16) unsigned short Ss[64 * 72];

  if (wv == 0) {
    int j = lane;
    float dt = dtv[(size_t)(base + j) * 8 + h];
    float A = -expf(Alog[h]);
    float s = dt * A;
#pragma unroll
    for (int off = 1; off < 64; off <<= 1) {
      float v = __shfl_up(s, off, 64);
      if (lane >= off) s += v;
    }
    float csl = __shfl(s, 63, 64);
    csc[j] = s; dts[j] = dt; ew[j] = expf(csl - s);
    csb[(size_t)blk * 64 + j] = s;
  }
  __syncthreads();

#pragma unroll
  for (int rr = 0; rr < 4; ++rr) {
    int j = rr * 16 + (tid >> 4);
    int pc = tid & 15;
    bf16x8_t v = *reinterpret_cast<const bf16x8_t*>(xBC + (size_t)(base + j) * 1152 + h * 128 + pc * 8);
    float dj = dts[j];
    int js = j ^ ((pc & 7) << 3);
#pragma unroll
    for (int e = 0; e < 8; ++e) {
      int p = pc * 8 + e;
      Xd[p * 72 + js] = f2bf(bf2f((unsigned short)v[e]) * dj);
    }
  }
#pragma unroll
  for (int rr = 0; rr < 2; ++rr) {
    int j = rr * 32 + (tid >> 3);
    int nc = tid & 7;
    bf16x8_t v = *reinterpret_cast<const bf16x8_t*>(xBC + (size_t)(base + j) * 1152 + 1024 + nc * 8);
    int js = j ^ ((nc & 7) << 3);
#pragma unroll
    for (int e = 0; e < 8; ++e) {
      int n = nc * 8 + e;
      Bnj[n * 72 + js] = (unsigned short)v[e];
    }
  }

  bf16x8_t cf[2];
  {
    size_t crow = (size_t)(base + wv * 16 + lr) * 1152 + 1088;
    cf[0] = *reinterpret_cast<const bf16x8_t*>(xBC + crow + lk * 8);
    cf[1] = *reinterpret_cast<const bf16x8_t*>(xBC + crow + 32 + lk * 8);
  }
  f32x4_t sacc[4];
#pragma unroll
  for (int jf = 0; jf < 4; ++jf) sacc[jf] = f32x4_t{0.f, 0.f, 0.f, 0.f};
#pragma unroll
  for (int ks = 0; ks < 2; ++ks) {
#pragma unroll
    for (int jf = 0; jf < 4; ++jf) {
      bf16x8_t bv = *reinterpret_cast<const bf16x8_t*>(
          xBC + (size_t)(base + jf * 16 + lr) * 1152 + 1024 + ks * 32 + lk * 8);
      sacc[jf] = __builtin_amdgcn_mfma_f32_16x16x32_bf16(cf[ks], bv, sacc[jf], 0, 0, 0);
    }
  }
  __syncthreads();

  {
    float csi[4];
#pragma unroll
    for (int r = 0; r < 4; ++r) csi[r] = csc[wv * 16 + lk * 4 + r];
#pragma unroll
    for (int jf = 0; jf < 4; ++jf) {
      int j = jf * 16 + lr;
      float csj = csc[j];
#pragma unroll
      for (int r = 0; r < 4; ++r) {
        int i = wv * 16 + lk * 4 + r;
        float w = (j <= i) ? expf(csi[r] - csj) : 0.f;
        Ss[i * 72 + j] = f2bf(sacc[jf][r] * w);
      }
    }
  }
  __syncthreads();

  f32x4_t yacc[8];
#pragma unroll
  for (int pf = 0; pf < 8; ++pf) yacc[pf] = f32x4_t{0.f, 0.f, 0.f, 0.f};
  bf16x8_t sa[2];
  sa[0] = *reinterpret_cast<const bf16x8_t*>(Ss + (wv * 16 + lr) * 72 + lk * 8);
  sa[1] = *reinterpret_cast<const bf16x8_t*>(Ss + (wv * 16 + lr) * 72 + 32 + lk * 8);
#pragma unroll
  for (int ks = 0; ks < 2; ++ks) {
    int jb = ks * 32 + lk * 8;
#pragma unroll
    for (int pf = 0; pf < 8; ++pf) {
      int p = pf * 16 + lr;
      bf16x8_t xv = *reinterpret_cast<const bf16x8_t*>(Xd + p * 72 + (jb ^ (((p >> 3) & 7) << 3)));
      yacc[pf] = __builtin_amdgcn_mfma_f32_16x16x32_bf16(sa[ks], xv, yacc[pf], 0, 0, 0);
    }
  }

  f32x4_t st[2][4];
#pragma unroll
  for (int pb = 0; pb < 2; ++pb)
#pragma unroll
    for (int nf = 0; nf < 4; ++nf) st[pb][nf] = f32x4_t{0.f, 0.f, 0.f, 0.f};
#pragma unroll
  for (int pb = 0; pb < 2; ++pb) {
    int p = wv * 32 + pb * 16 + lr;
#pragma unroll
    for (int ks = 0; ks < 2; ++ks) {
      int jb = ks * 32 + lk * 8;
      bf16x8_t xv = *reinterpret_cast<const bf16x8_t*>(Xd + p * 72 + (jb ^ (((p >> 3) & 7) << 3)));
      bf16x8_t xs;
#pragma unroll
      for (int e = 0; e < 8; ++e) xs[e] = (short)f2bf(bf2f((unsigned short)xv[e]) * ew[jb + e]);
#pragma unroll
      for (int nf = 0; nf < 4; ++nf) {
        int n = nf * 16 + lr;
        bf16x8_t bv = *reinterpret_cast<const bf16x8_t*>(Bnj + n * 72 + (jb ^ (((n >> 3) & 7) << 3)));
        st[pb][nf] = __builtin_amdgcn_mfma_f32_16x16x32_bf16(xs, bv, st[pb][nf], 0, 0, 0);
      }
    }
  }

#pragma unroll
  for (int pf = 0; pf < 8; ++pf)
#pragma unroll
    for (int r = 0; r < 4; ++r) {
      int i = wv * 16 + lk * 4 + r;
      ypart[(size_t)(base + i) * 1024 + h * 128 + pf * 16 + lr] = f2bf(yacc[pf][r]);
    }
  unsigned short* so = stat + (size_t)blk * 8192;
#pragma unroll
  for (int pb = 0; pb < 2; ++pb)
#pragma unroll
    for (int nf = 0; nf < 4; ++nf)
#pragma unroll
      for (int r = 0; r < 4; ++r)
        so[(size_t)(wv * 32 + pb * 16 + lk * 4 + r) * 64 + nf * 16 + lr] = f2bf(st[pb][nf][r]);
}

// ---------------- element-parallel inter-chunk scan (64 chunks), prev -> bf16 ----------------
__global__ __launch_bounds__(256) void scan_kernel(const unsigned short* __restrict__ stat,
                                                   const float* __restrict__ csb,
                                                   unsigned short* __restrict__ prevb) {
  int bh = blockIdx.x >> 5;
  int part = blockIdx.x & 31;
  int h = bh & 7, b = bh >> 3;
  int e = part * 256 + threadIdx.x;
  float carry = 0.f;
  for (int c = 0; c < 64; ++c) {
    size_t blk = (size_t)(b * 64 + c) * 8 + h;
    size_t idx = blk * 8192 + e;
    prevb[idx] = f2bf(carry);
    float dec = expf(csb[blk * 64 + 63]);
    carry = bf2f(stat[idx]) + dec * carry;
  }
}

// ==== fused SSD pass 2 + RMSNorm: per block 16 rows x all heads; wave = head ====
// y = ypart + (C e^cs) @ prev^T + D x ; out = concat(y,z) * rsqrt(mean(sq)) * nw
__global__ __launch_bounds__(512) void ssd2_norm_kernel(const unsigned short* __restrict__ xBC,
                                                        const float* __restrict__ csb,
                                                        const unsigned short* __restrict__ prevb,
                                                        const float* __restrict__ Dp,
                                                        const unsigned short* __restrict__ ypart,
                                                        const unsigned short* __restrict__ zc,
                                                        const float* __restrict__ nw,
                                                        unsigned short* __restrict__ out) {
  __shared__ __align__(16) unsigned short ysm[16 * 1032];   // row stride 1032 elems (16B-aligned)
  __shared__ float ssq[16];
  __shared__ float sfac[16];
  int tid = threadIdx.x, lane = tid & 63, h = tid >> 6;      // wave index = head
  int lr = lane & 15, lk = lane >> 4;
  int R0 = blockIdx.x * 16;
  int b = R0 >> 12;
  int r4 = R0 & 4095;
  int c = r4 >> 6;
  int q0 = r4 & 63;                                          // in-chunk offset (0,16,32,48)
  int blkh = (b * 64 + c) * 8 + h;

  if (tid < 16) ssq[tid] = 0.f;
  __syncthreads();

  float Dh = Dp[h];
  // Cd fragment (rows R0+lr), scaled by exp(cs_i)
  float sc = expf(csb[(size_t)blkh * 64 + q0 + lr]);
  bf16x8_t ca[2];
  {
    size_t crow = (size_t)(R0 + lr) * 1152 + 1088;
#pragma unroll
    for (int ks = 0; ks < 2; ++ks) {
      bf16x8_t v = *reinterpret_cast<const bf16x8_t*>(xBC + crow + ks * 32 + lk * 8);
      bf16x8_t d;
#pragma unroll
      for (int e = 0; e < 8; ++e) d[e] = (short)f2bf(bf2f((unsigned short)v[e]) * sc);
      ca[ks] = d;
    }
  }
  f32x4_t acc[8];
#pragma unroll
  for (int pf = 0; pf < 8; ++pf) acc[pf] = f32x4_t{0.f, 0.f, 0.f, 0.f};
#pragma unroll
  for (int ks = 0; ks < 2; ++ks) {
#pragma unroll
    for (int pf = 0; pf < 8; ++pf) {
      bf16x8_t pv = *reinterpret_cast<const bf16x8_t*>(
          prevb + (size_t)blkh * 8192 + (size_t)(pf * 16 + lr) * 64 + ks * 32 + lk * 8);
      acc[pf] = __builtin_amdgcn_mfma_f32_16x16x32_bf16(ca[ks], pv, acc[pf], 0, 0, 0);
    }
  }

  // epilogue: y values, per-row sum of squares, stash y in LDS
#pragma unroll
  for (int r = 0; r < 4; ++r) {
    int row = lk * 4 + r;                 // 0..15
    size_t R = (size_t)(R0 + row);
    float partial = 0.f;
#pragma unroll
    for (int pf = 0; pf < 8; ++pf) {
      int p = pf * 16 + lr;
      float xr = bf2f(xBC[R * 1152 + h * 128 + p]);
      float yv = bf2f(ypart[R * 1024 + h * 128 + p]) + acc[pf][r] + Dh * xr;
      partial += yv * yv;
      ysm[row * 1032 + h * 128 + p] = f2bf(yv);
    }
#pragma unroll
    for (int m = 1; m < 16; m <<= 1) partial += __shfl_xor(partial, m, 64);
    if (lr == 0) atomicAdd(&ssq[row], partial);
  }

  // z: thread covers row tid>>5, 4 chunks of 8 elems at col k*256 + (tid&31)*8
  int zr = tid >> 5, sub = tid & 31;
  size_t Rz = (size_t)(R0 + zr);
  bf16x8_t zv[4];
  float zpart = 0.f;
#pragma unroll
  for (int k = 0; k < 4; ++k) {
    zv[k] = *reinterpret_cast<const bf16x8_t*>(zc + Rz * 1024 + k * 256 + sub * 8);
#pragma unroll
    for (int e = 0; e < 8; ++e) { float z = bf2f((unsigned short)zv[k][e]); zpart += z * z; }
  }
  atomicAdd(&ssq[zr], zpart);
  __syncthreads();
  if (tid < 16) sfac[tid] = rsqrtf(ssq[tid] * (1.f / 2048.f) + 1e-5f);
  __syncthreads();

  float s = sfac[zr];
#pragma unroll
  for (int k = 0; k < 4; ++k) {
    int col = k * 256 + sub * 8;
    bf16x8_t y8 = *reinterpret_cast<const bf16x8_t*>(ysm + zr * 1032 + col);
    float4 wy0 = *reinterpret_cast<const float4*>(nw + col);
    float4 wy1 = *reinterpret_cast<const float4*>(nw + col + 4);
    bf16x8_t oy;
    oy[0] = (short)f2bf(bf2f((unsigned short)y8[0]) * s * wy0.x);
    oy[1] = (short)f2bf(bf2f((unsigned short)y8[1]) * s * wy0.y);
    oy[2] = (short)f2bf(bf2f((unsigned short)y8[2]) * s * wy0.z);
    oy[3] = (short)f2bf(bf2f((unsigned short)y8[3]) * s * wy0.w);
    oy[4] = (short)f2bf(bf2f((unsigned short)y8[4]) * s * wy1.x);
    oy[5] = (short)f2bf(bf2f((unsigned short)y8[5]) * s * wy1.y);
    oy[6] = (short)f2bf(bf2f((unsigned short)y8[6]) * s * wy1.z);
    oy[7] = (short)f2bf(bf2f((unsigned short)y8[7]) * s * wy1.w);
    *reinterpret_cast<bf16x8_t*>(out + Rz * 2048 + col) = oy;

    float4 wz0 = *reinterpret_cast<const float4*>(nw + 1024 + col);
    float4 wz1 = *reinterpret_cast<const float4*>(nw + 1024 + col + 4);
    bf16x8_t oz;
    oz[0] = (short)f2bf(bf2f((unsigned short)zv[k][0]) * s * wz0.x);
    oz[1] = (short)f2bf(bf2f((unsigned short)zv[k][1]) * s * wz0.y);
    oz[2] = (short)f2bf(bf2f((unsigned short)zv[k][2]) * s * wz0.z);
    oz[3] = (short)f2bf(bf2f((unsigned short)zv[k][3]) * s * wz0.w);
    oz[4] = (short)f2bf(bf2f((unsigned short)zv[k][4]) * s * wz1.x);
    oz[5] = (short)f2bf(bf2f((unsigned short)zv[k][5]) * s * wz1.y);
    oz[6] = (short)f2bf(bf2f((unsigned short)zv[k][6]) * s * wz1.z);
    oz[7] = (short)f2bf(bf2f((unsigned short)zv[k][7]) * s * wz1.w);
    *reinterpret_cast<bf16x8_t*>(out + Rz * 2048 + 1024 + col) = oz;
  }
}

extern "C" void kernel_launch(void* const* d_in, const int* in_sizes, int n_in,
                              void* d_out, int out_size, void* d_ws, size_t ws_size,
                              hipStream_t stream) {
  const float* u       = (const float*)d_in[0];
  const float* W_in    = (const float*)d_in[1];
  const float* xconv_w = (const float*)d_in[2];
  const float* xconv_b = (const float*)d_in[3];
  const float* zconv_w = (const float*)d_in[4];
  const float* zconv_b = (const float*)d_in[5];
  const float* dt_bias = (const float*)d_in[6];
  const float* Alog    = (const float*)d_in[7];
  const float* Dp      = (const float*)d_in[8];
  const float* norm_w  = (const float*)d_in[9];
  const float* W_out   = (const float*)d_in[10];
  float* out = (float*)d_out;

  char* ws = (char*)d_ws;
  size_t o = 0;
  auto alc = [&](size_t bytes) { void* p = (void*)(ws + o); o = (o + bytes + 255) & ~(size_t)255; return p; };
  unsigned short* A1     = (unsigned short*)alc(16777216);  // u bf16
  unsigned short* Wt1    = (unsigned short*)alc(4718592);   // W_in^T padded (2304 x 1024)
  unsigned short* Wt2    = (unsigned short*)alc(4194304);   // W_out^T (1024 x 2048)
  char* regZ = (char*)alc(37748736);    // zx (bf16 8192x2304) -> ypart (bf16, zx dead after convs)
  float*          dtv    = (float*)alc(262144);
  float*          csb    = (float*)alc(262144);
  unsigned short* xBC    = (unsigned short*)alc(18874368);  // 8192x1152 bf16
  unsigned short* zc     = (unsigned short*)alc(16777216);  // 8192x1024 bf16
  char* regS = (char*)alc(33554432);    // stat (bf16) -> normed (bf16 8192x2048)
  unsigned short* prevb  = (unsigned short*)alc(16777216);
  float*          Wdt    = (float*)alc(32768);              // 8 x 1024 fp32
  (void)ws_size; (void)in_sizes; (void)n_in; (void)out_size;

  unsigned short* zx     = (unsigned short*)regZ;
  unsigned short* ypart  = (unsigned short*)regZ;   // reuses zx region after convs consume it
  unsigned short* stat   = (unsigned short*)regS;
  unsigned short* normed = (unsigned short*)regS;

  dim3 tb(32, 8);
  wdt_kernel<<<4, 256, 0, stream>>>(W_in, Wdt);
  uin_kernel<<<2048, 256, 0, stream>>>(u, Wdt, dt_bias, A1, dtv);
  transpose_bf16_kernel<<<dim3(72, 32), tb, 0, stream>>>(W_in, Wt1, 1024, 2176, 2184);
  transpose_bf16_kernel<<<dim3(32, 64), tb, 0, stream>>>(W_out, Wt2, 2048, 1024, 1024);
  gemm_tb_kernel<1><<<576, 512, 0, stream>>>(A1, Wt1, (void*)zx, 1024, 2304, 64);
  conv_silu_tile_kernel<1152, 2304><<<576, 256, 0, stream>>>(zx + 1024, xconv_w, xconv_b, xBC);
  conv_silu_tile_kernel<1024, 2304><<<512, 256, 0, stream>>>(zx, zconv_w, zconv_b, zc);
  ssd1_kernel<<<1024, 256, 0, stream>>>(xBC, dtv, Alog, csb, stat, ypart);
  scan_kernel<<<512, 256, 0, stream>>>(stat, csb, prevb);
  ssd2_norm_kernel<<<512, 512, 0, stream>>>(xBC, csb, prevb, Dp, ypart, zc, norm_w, normed);
  gemm_tb_kernel<0><<<256, 512, 0, stream>>>(normed, Wt2, (void*)out, 2048, 1024, 64);
}

// Round 17
// 222.162 us; speedup vs baseline: 1.0359x; 1.0110x over previous
//
#include <hip/hip_runtime.h>
#include <stdint.h>

#define DEV __device__ __forceinline__

typedef __attribute__((ext_vector_type(8))) short bf16x8_t;   // 8 bf16 in 4 VGPRs
typedef __attribute__((ext_vector_type(4))) float f32x4_t;

DEV unsigned short f2bf(float f) {
  union { float f; uint32_t u; } x; x.f = f;
  uint32_t r = x.u + 0x7fffu + ((x.u >> 16) & 1u);
  return (unsigned short)(r >> 16);
}
DEV float bf2f(unsigned short u) {
  union { uint32_t u; float f; } x; x.u = ((uint32_t)u) << 16;
  return x.f;
}

#define GLOAD_LDS16(g, l)                                                              \
  __builtin_amdgcn_global_load_lds((const __attribute__((address_space(1))) unsigned int*)(g), \
                                   (__attribute__((address_space(3))) unsigned int*)(l), 16, 0, 0)

// ---------------- one-time gather: Wdt[h][k] = W_in[k][2176+h] ----------------
__global__ __launch_bounds__(256) void wdt_kernel(const float* __restrict__ W_in, float* __restrict__ Wdt) {
  int k = blockIdx.x * 256 + threadIdx.x;
  if (k < 1024) {
#pragma unroll
    for (int h = 0; h < 8; ++h)
      Wdt[h * 1024 + k] = W_in[(size_t)k * 2184 + 2176 + h];
  }
}

// ---------------- fused: u -> bf16 copy + dt = softplus(u @ Wdt^T + dt_bias), 4 rows/block ----------------
__global__ __launch_bounds__(256) void uin_kernel(const float* __restrict__ u, const float* __restrict__ Wdt,
                                                  const float* __restrict__ dt_bias,
                                                  unsigned short* __restrict__ A1, float* __restrict__ dtv) {
  int tid = threadIdx.x;
  int row0 = blockIdx.x * 4;
  int lane = tid & 63, wv = tid >> 6;
  float4 w4[8];
#pragma unroll
  for (int h = 0; h < 8; ++h) w4[h] = reinterpret_cast<const float4*>(Wdt + h * 1024)[tid];
  __shared__ float red[4][8];
#pragma unroll
  for (int r = 0; r < 4; ++r) {
    int row = row0 + r;
    float4 v = reinterpret_cast<const float4*>(u + (size_t)row * 1024)[tid];
    ushort4 o;
    o.x = f2bf(v.x); o.y = f2bf(v.y); o.z = f2bf(v.z); o.w = f2bf(v.w);
    reinterpret_cast<ushort4*>(A1 + (size_t)row * 1024)[tid] = o;
    float ps[8];
#pragma unroll
    for (int h = 0; h < 8; ++h)
      ps[h] = v.x * w4[h].x + v.y * w4[h].y + v.z * w4[h].z + v.w * w4[h].w;
#pragma unroll
    for (int h = 0; h < 8; ++h)
#pragma unroll
      for (int off = 32; off > 0; off >>= 1) ps[h] += __shfl_down(ps[h], off, 64);
    if (lane == 0) {
#pragma unroll
      for (int h = 0; h < 8; ++h) red[wv][h] = ps[h];
    }
    __syncthreads();
    if (tid < 8) {
      float s = red[0][tid] + red[1][tid] + red[2][tid] + red[3][tid] + dt_bias[tid];
      float sp = (s > 20.f) ? s : log1pf(expf(s));
      dtv[(size_t)row * 8 + tid] = sp;
    }
    __syncthreads();
  }
}

// ---------------- transpose fp32 (R x Cin, row stride) -> bf16 (C x R), zero-pad ----------------
__global__ void transpose_bf16_kernel(const float* __restrict__ in, unsigned short* __restrict__ out,
                                      int R, int Cin, int stride) {
  __shared__ float t[32][33];
  int bx = blockIdx.x, by = blockIdx.y;
  int tx = threadIdx.x, ty = threadIdx.y;
#pragma unroll
  for (int q = 0; q < 4; ++q) {
    int r = by * 32 + ty + q * 8, c = bx * 32 + tx;
    t[ty + q * 8][tx] = (c < Cin) ? in[(size_t)r * stride + c] : 0.f;
  }
  __syncthreads();
#pragma unroll
  for (int q = 0; q < 4; ++q) {
    int oc = bx * 32 + ty + q * 8;
    int orr = by * 32 + tx;
    out[(size_t)oc * R + orr] = f2bf(t[tx][ty + q * 8]);
  }
}

// ======== 128x256 MFMA GEMM, BK=32, counted-vmcnt TRIPLE buffer, 8 waves, 72KB LDS ========
// Chunk-XOR (round-8-verified): slot s of row r holds k-chunk (s ^ ((r>>1)&3)); staging lane-monotonic.
// Schedule per K-step t: barrier1 -> STAGE(t+2) -> vmcnt(6) -> barrier2 -> 12 ds_read + 16 MFMA.
template <int OBF>
__global__ __launch_bounds__(512) void gemm_tb_kernel(const unsigned short* __restrict__ A,
                                                      const unsigned short* __restrict__ Bt,
                                                      void* __restrict__ Cout, int K, int ldc, int gx) {
  __shared__ __align__(16) char lds[3 * 24576];
  int tid = threadIdx.x, lane = tid & 63, wv = tid >> 6;
  int lr = lane & 15, lk = lane >> 4;
  int wm = wv >> 2, wn = wv & 3;

  int nwg = gridDim.x, lin = blockIdx.x, wg = lin;
  if ((nwg & 7) == 0) { int cpx = nwg >> 3; wg = (lin & 7) * cpx + (lin >> 3); }
  long tileM = (long)(wg % gx) * 128;
  long tileN = (long)(wg / gx) * 256;

  const unsigned short* gAp;
  {
    int q = tid, row = q >> 2, c = (q & 3) ^ ((row >> 1) & 3);
    gAp = A + (size_t)(tileM + row) * K + c * 8;
  }
  const unsigned short* gBp[2];
#pragma unroll
  for (int i = 0; i < 2; ++i) {
    int q = tid + i * 512, row = q >> 2, c = (q & 3) ^ ((row >> 1) & 3);
    gBp[i] = Bt + (size_t)(tileN + row) * K + c * 8;
  }

#define STAGE_TB(bsel, kof)                                                                  \
  do {                                                                                       \
    GLOAD_LDS16(gAp + (kof), lds + (bsel) * 24576 + tid * 16);                               \
    _Pragma("unroll") for (int i_ = 0; i_ < 2; ++i_)                                         \
        GLOAD_LDS16(gBp[i_] + (kof), lds + (bsel) * 24576 + 8192 + (tid + i_ * 512) * 16);   \
  } while (0)

  f32x4_t acc[4][4];
#pragma unroll
  for (int i = 0; i < 4; ++i)
#pragma unroll
    for (int j = 0; j < 4; ++j) acc[i][j] = f32x4_t{0.f, 0.f, 0.f, 0.f};

  int NT = K >> 5;
  STAGE_TB(0, 0);       // prologue: tiles 0,1 -> bufs 0,1
  STAGE_TB(1, 32);

  int colsw = ((lk ^ ((lr >> 1) & 3)) << 4);
  int rsel = 0, wsel = 2;
  for (int t = 0; t < NT; ++t) {
    __builtin_amdgcn_s_barrier();
    if (t + 2 < NT) {
      STAGE_TB(wsel, (t + 2) * 32);
      asm volatile("s_waitcnt vmcnt(6)" ::: "memory");
    } else if (t + 1 < NT) {
      asm volatile("s_waitcnt vmcnt(3)" ::: "memory");
    } else {
      asm volatile("s_waitcnt vmcnt(0)" ::: "memory");
    }
    __builtin_amdgcn_s_barrier();

    const char* base = lds + rsel * 24576;
    bf16x8_t a[4], b[4];
#pragma unroll
    for (int mf = 0; mf < 4; ++mf)
      a[mf] = *reinterpret_cast<const bf16x8_t*>(base + (wm * 64 + mf * 16 + lr) * 64 + colsw);
#pragma unroll
    for (int nf = 0; nf < 4; ++nf)
      b[nf] = *reinterpret_cast<const bf16x8_t*>(base + 8192 + (wn * 64 + nf * 16 + lr) * 64 + colsw);
    __builtin_amdgcn_s_setprio(1);
#pragma unroll
    for (int mf = 0; mf < 4; ++mf)
#pragma unroll
      for (int nf = 0; nf < 4; ++nf)
        acc[mf][nf] = __builtin_amdgcn_mfma_f32_16x16x32_bf16(a[mf], b[nf], acc[mf][nf], 0, 0, 0);
    __builtin_amdgcn_s_setprio(0);
    rsel = (rsel == 2) ? 0 : rsel + 1;
    wsel = (wsel == 2) ? 0 : wsel + 1;
  }
#undef STAGE_TB

#pragma unroll
  for (int mf = 0; mf < 4; ++mf)
#pragma unroll
    for (int nf = 0; nf < 4; ++nf) {
      long r0 = tileM + wm * 64 + mf * 16 + lk * 4;
      long c0 = tileN + wn * 64 + nf * 16 + lr;
#pragma unroll
      for (int r = 0; r < 4; ++r) {
        if (OBF)
          ((unsigned short*)Cout)[(size_t)(r0 + r) * ldc + c0] = f2bf(acc[mf][nf][r]);
        else
          ((float*)Cout)[(size_t)(r0 + r) * ldc + c0] = acc[mf][nf][r];
      }
    }
}

// ---------------- causal dwconv(4)+SiLU, register-tiled: 8 t x 8 ch per thread ----------------
template <int C, int IN_STRIDE>
__global__ __launch_bounds__(256) void conv_silu_tile_kernel(const unsigned short* __restrict__ in,
                                                             const float* __restrict__ w,
                                                             const float* __restrict__ bias,
                                                             unsigned short* __restrict__ outp) {
  constexpr int CG = C / 8;
  int idx = blockIdx.x * 256 + threadIdx.x;
  int ch_grp = idx % CG;
  int tb = idx / CG;
  int t0 = (tb & 511) * 8;
  int b = tb >> 9;
  int ch0 = ch_grp * 8;

  float4 wv[8];
#pragma unroll
  for (int e = 0; e < 8; ++e) wv[e] = *reinterpret_cast<const float4*>(w + (ch0 + e) * 4);
  float bs[8];
  {
    float4 b0 = *reinterpret_cast<const float4*>(bias + ch0);
    float4 b1 = *reinterpret_cast<const float4*>(bias + ch0 + 4);
    bs[0] = b0.x; bs[1] = b0.y; bs[2] = b0.z; bs[3] = b0.w;
    bs[4] = b1.x; bs[5] = b1.y; bs[6] = b1.z; bs[7] = b1.w;
  }

  float rows[11][8];
#pragma unroll
  for (int k = 0; k < 11; ++k) {
    int t = t0 - 3 + k;
    if (t >= 0) {
      bf16x8_t v = *reinterpret_cast<const bf16x8_t*>(in + (size_t)((b << 12) + t) * IN_STRIDE + ch0);
#pragma unroll
      for (int e = 0; e < 8; ++e) rows[k][e] = bf2f((unsigned short)v[e]);
    } else {
#pragma unroll
      for (int e = 0; e < 8; ++e) rows[k][e] = 0.f;
    }
  }

#pragma unroll
  for (int tp = 0; tp < 8; ++tp) {
    bf16x8_t o;
#pragma unroll
    for (int e = 0; e < 8; ++e) {
      float a = bs[e] + wv[e].x * rows[tp][e] + wv[e].y * rows[tp + 1][e] +
                wv[e].z * rows[tp + 2][e] + wv[e].w * rows[tp + 3][e];
      a = a / (1.f + expf(-a));
      o[e] = (short)f2bf(a);
    }
    *reinterpret_cast<bf16x8_t*>(outp + (size_t)((b << 12) + t0 + tp) * C + ch0) = o;
  }
}

// ---------------- SSD pass 1 (chunk=64): cumsum + S + Y_diag + chunk states ----------------
__global__ __launch_bounds__(256) void ssd1_kernel(const unsigned short* __restrict__ xBC,
                                                   const float* __restrict__ dtv,
                                                   const float* __restrict__ Alog,
                                                   float* __restrict__ csb,
                                                   unsigned short* __restrict__ stat,
                                                   unsigned short* __restrict__ ypart) {
  int blk = blockIdx.x;
  int h = blk & 7, bc = blk >> 3;
  int c = bc & 63, b = bc >> 6;
  int tid = threadIdx.x, lane = tid & 63, wv = tid >> 6;
  int lr = lane & 15, lk = lane >> 4;
  int base = b * 4096 + c * 64;

  __shared__ float csc[64], dts[64], ew[64];
  __shared__ __align__(16) unsigned short Xd[128 * 72];
  __shared__ __align__(16) unsigned short Bnj[64 * 72];
  __shared__ __align__(16) unsigned short Ss[64 * 72];

  if (wv == 0) {
    int j = lane;
    float dt = dtv[(size_t)(base + j) * 8 + h];
    float A = -expf(Alog[h]);
    float s = dt * A;
#pragma unroll
    for (int off = 1; off < 64; off <<= 1) {
      float v = __shfl_up(s, off, 64);
      if (lane >= off) s += v;
    }
    float csl = __shfl(s, 63, 64);
    csc[j] = s; dts[j] = dt; ew[j] = expf(csl - s);
    csb[(size_t)blk * 64 + j] = s;
  }
  __syncthreads();

#pragma unroll
  for (int rr = 0; rr < 4; ++rr) {
    int j = rr * 16 + (tid >> 4);
    int pc = tid & 15;
    bf16x8_t v = *reinterpret_cast<const bf16x8_t*>(xBC + (size_t)(base + j) * 1152 + h * 128 + pc * 8);
    float dj = dts[j];
    int js = j ^ ((pc & 7) << 3);
#pragma unroll
    for (int e = 0; e < 8; ++e) {
      int p = pc * 8 + e;
      Xd[p * 72 + js] = f2bf(bf2f((unsigned short)v[e]) * dj);
    }
  }
#pragma unroll
  for (int rr = 0; rr < 2; ++rr) {
    int j = rr * 32 + (tid >> 3);
    int nc = tid & 7;
    bf16x8_t v = *reinterpret_cast<const bf16x8_t*>(xBC + (size_t)(base + j) * 1152 + 1024 + nc * 8);
    int js = j ^ ((nc & 7) << 3);
#pragma unroll
    for (int e = 0; e < 8; ++e) {
      int n = nc * 8 + e;
      Bnj[n * 72 + js] = (unsigned short)v[e];
    }
  }

  bf16x8_t cf[2];
  {
    size_t crow = (size_t)(base + wv * 16 + lr) * 1152 + 1088;
    cf[0] = *reinterpret_cast<const bf16x8_t*>(xBC + crow + lk * 8);
    cf[1] = *reinterpret_cast<const bf16x8_t*>(xBC + crow + 32 + lk * 8);
  }
  f32x4_t sacc[4];
#pragma unroll
  for (int jf = 0; jf < 4; ++jf) sacc[jf] = f32x4_t{0.f, 0.f, 0.f, 0.f};
#pragma unroll
  for (int ks = 0; ks < 2; ++ks) {
#pragma unroll
    for (int jf = 0; jf < 4; ++jf) {
      bf16x8_t bv = *reinterpret_cast<const bf16x8_t*>(
          xBC + (size_t)(base + jf * 16 + lr) * 1152 + 1024 + ks * 32 + lk * 8);
      sacc[jf] = __builtin_amdgcn_mfma_f32_16x16x32_bf16(cf[ks], bv, sacc[jf], 0, 0, 0);
    }
  }
  __syncthreads();

  {
    float csi[4];
#pragma unroll
    for (int r = 0; r < 4; ++r) csi[r] = csc[wv * 16 + lk * 4 + r];
#pragma unroll
    for (int jf = 0; jf < 4; ++jf) {
      int j = jf * 16 + lr;
      float csj = csc[j];
#pragma unroll
      for (int r = 0; r < 4; ++r) {
        int i = wv * 16 + lk * 4 + r;
        float w = (j <= i) ? expf(csi[r] - csj) : 0.f;
        Ss[i * 72 + j] = f2bf(sacc[jf][r] * w);
      }
    }
  }
  __syncthreads();

  f32x4_t yacc[8];
#pragma unroll
  for (int pf = 0; pf < 8; ++pf) yacc[pf] = f32x4_t{0.f, 0.f, 0.f, 0.f};
  bf16x8_t sa[2];
  sa[0] = *reinterpret_cast<const bf16x8_t*>(Ss + (wv * 16 + lr) * 72 + lk * 8);
  sa[1] = *reinterpret_cast<const bf16x8_t*>(Ss + (wv * 16 + lr) * 72 + 32 + lk * 8);
#pragma unroll
  for (int ks = 0; ks < 2; ++ks) {
    int jb = ks * 32 + lk * 8;
#pragma unroll
    for (int pf = 0; pf < 8; ++pf) {
      int p = pf * 16 + lr;
      bf16x8_t xv = *reinterpret_cast<const bf16x8_t*>(Xd + p * 72 + (jb ^ (((p >> 3) & 7) << 3)));
      yacc[pf] = __builtin_amdgcn_mfma_f32_16x16x32_bf16(sa[ks], xv, yacc[pf], 0, 0, 0);
    }
  }

  f32x4_t st[2][4];
#pragma unroll
  for (int pb = 0; pb < 2; ++pb)
#pragma unroll
    for (int nf = 0; nf < 4; ++nf) st[pb][nf] = f32x4_t{0.f, 0.f, 0.f, 0.f};
#pragma unroll
  for (int pb = 0; pb < 2; ++pb) {
    int p = wv * 32 + pb * 16 + lr;
#pragma unroll
    for (int ks = 0; ks < 2; ++ks) {
      int jb = ks * 32 + lk * 8;
      bf16x8_t xv = *reinterpret_cast<const bf16x8_t*>(Xd + p * 72 + (jb ^ (((p >> 3) & 7) << 3)));
      bf16x8_t xs;
#pragma unroll
      for (int e = 0; e < 8; ++e) xs[e] = (short)f2bf(bf2f((unsigned short)xv[e]) * ew[jb + e]);
#pragma unroll
      for (int nf = 0; nf < 4; ++nf) {
        int n = nf * 16 + lr;
        bf16x8_t bv = *reinterpret_cast<const bf16x8_t*>(Bnj + n * 72 + (jb ^ (((n >> 3) & 7) << 3)));
        st[pb][nf] = __builtin_amdgcn_mfma_f32_16x16x32_bf16(xs, bv, st[pb][nf], 0, 0, 0);
      }
    }
  }

#pragma unroll
  for (int pf = 0; pf < 8; ++pf)
#pragma unroll
    for (int r = 0; r < 4; ++r) {
      int i = wv * 16 + lk * 4 + r;
      ypart[(size_t)(base + i) * 1024 + h * 128 + pf * 16 + lr] = f2bf(yacc[pf][r]);
    }
  unsigned short* so = stat + (size_t)blk * 8192;
#pragma unroll
  for (int pb = 0; pb < 2; ++pb)
#pragma unroll
    for (int nf = 0; nf < 4; ++nf)
#pragma unroll
      for (int r = 0; r < 4; ++r)
        so[(size_t)(wv * 32 + pb * 16 + lk * 4 + r) * 64 + nf * 16 + lr] = f2bf(st[pb][nf][r]);
}

// ---------------- element-parallel inter-chunk scan (64 chunks), prev -> bf16 ----------------
__global__ __launch_bounds__(256) void scan_kernel(const unsigned short* __restrict__ stat,
                                                   const float* __restrict__ csb,
                                                   unsigned short* __restrict__ prevb) {
  int bh = blockIdx.x >> 5;
  int part = blockIdx.x & 31;
  int h = bh & 7, b = bh >> 3;
  int e = part * 256 + threadIdx.x;
  float carry = 0.f;
  for (int c = 0; c < 64; ++c) {
    size_t blk = (size_t)(b * 64 + c) * 8 + h;
    size_t idx = blk * 8192 + e;
    prevb[idx] = f2bf(carry);
    float dec = expf(csb[blk * 64 + 63]);
    carry = bf2f(stat[idx]) + dec * carry;
  }
}

// ---------------- SSD pass 2: Y = ypart + (C e^cs) @ prev^T + D x ----------------
__global__ __launch_bounds__(256) void ssd2_kernel(const unsigned short* __restrict__ xBC,
                                                   const float* __restrict__ csb,
                                                   const unsigned short* __restrict__ prevb,
                                                   const float* __restrict__ Dp,
                                                   const unsigned short* __restrict__ ypart,
                                                   unsigned short* __restrict__ yb) {
  int blk = blockIdx.x;
  int h = blk & 7, bc = blk >> 3;
  int c = bc & 63, b = bc >> 6;
  int tid = threadIdx.x, lane = tid & 63, wv = tid >> 6;
  int lr = lane & 15, lk = lane >> 4;
  int base = b * 4096 + c * 64;
  __shared__ float csc[64];
  if (tid < 64) csc[tid] = csb[(size_t)blk * 64 + tid];
  __syncthreads();

  float sc = expf(csc[wv * 16 + lr]);
  bf16x8_t ca[2];
  {
    size_t crow = (size_t)(base + wv * 16 + lr) * 1152 + 1088;
#pragma unroll
    for (int ks = 0; ks < 2; ++ks) {
      bf16x8_t v = *reinterpret_cast<const bf16x8_t*>(xBC + crow + ks * 32 + lk * 8);
      bf16x8_t d;
#pragma unroll
      for (int e = 0; e < 8; ++e) d[e] = (short)f2bf(bf2f((unsigned short)v[e]) * sc);
      ca[ks] = d;
    }
  }
  f32x4_t acc[8];
#pragma unroll
  for (int pf = 0; pf < 8; ++pf) acc[pf] = f32x4_t{0.f, 0.f, 0.f, 0.f};
#pragma unroll
  for (int ks = 0; ks < 2; ++ks) {
#pragma unroll
    for (int pf = 0; pf < 8; ++pf) {
      bf16x8_t pv = *reinterpret_cast<const bf16x8_t*>(
          prevb + (size_t)blk * 8192 + (size_t)(pf * 16 + lr) * 64 + ks * 32 + lk * 8);
      acc[pf] = __builtin_amdgcn_mfma_f32_16x16x32_bf16(ca[ks], pv, acc[pf], 0, 0, 0);
    }
  }
  float Dh = Dp[h];
#pragma unroll
  for (int pf = 0; pf < 8; ++pf)
#pragma unroll
    for (int r = 0; r < 4; ++r) {
      int i = wv * 16 + lk * 4 + r;
      size_t row = (size_t)(base + i);
      int p = pf * 16 + lr;
      float xr = bf2f(xBC[row * 1152 + h * 128 + p]);
      float yv = bf2f(ypart[row * 1024 + h * 128 + p]) + acc[pf][r] + Dh * xr;
      yb[row * 1024 + h * 128 + p] = f2bf(yv);
    }
}

// ---------------- RMSNorm over concat(y, z) bf16 -> bf16 ----------------
__global__ __launch_bounds__(256) void rmsnorm_kernel(const unsigned short* __restrict__ y,
                                                      const unsigned short* __restrict__ z,
                                                      const float* __restrict__ nw,
                                                      unsigned short* __restrict__ out) {
  int row = blockIdx.x, tid = threadIdx.x;
  ushort4 ya = reinterpret_cast<const ushort4*>(y + (size_t)row * 1024)[tid];
  ushort4 za = reinterpret_cast<const ushort4*>(z + (size_t)row * 1024)[tid];
  float yf[4] = {bf2f(ya.x), bf2f(ya.y), bf2f(ya.z), bf2f(ya.w)};
  float zf[4] = {bf2f(za.x), bf2f(za.y), bf2f(za.z), bf2f(za.w)};
  float ss = yf[0] * yf[0] + yf[1] * yf[1] + yf[2] * yf[2] + yf[3] * yf[3] +
             zf[0] * zf[0] + zf[1] * zf[1] + zf[2] * zf[2] + zf[3] * zf[3];
#pragma unroll
  for (int off = 32; off > 0; off >>= 1) ss += __shfl_down(ss, off, 64);
  __shared__ float red[4];
  __shared__ float stot;
  int lane = tid & 63, wv = tid >> 6;
  if (lane == 0) red[wv] = ss;
  __syncthreads();
  if (tid == 0) stot = rsqrtf((red[0] + red[1] + red[2] + red[3]) * (1.f / 2048.f) + 1e-5f);
  __syncthreads();
  float s = stot;
  float4 w1 = reinterpret_cast<const float4*>(nw)[tid];
  float4 w2 = reinterpret_cast<const float4*>(nw + 1024)[tid];
  ushort4 o1, o2;
  o1.x = f2bf(yf[0] * s * w1.x); o1.y = f2bf(yf[1] * s * w1.y);
  o1.z = f2bf(yf[2] * s * w1.z); o1.w = f2bf(yf[3] * s * w1.w);
  o2.x = f2bf(zf[0] * s * w2.x); o2.y = f2bf(zf[1] * s * w2.y);
  o2.z = f2bf(zf[2] * s * w2.z); o2.w = f2bf(zf[3] * s * w2.w);
  reinterpret_cast<ushort4*>(out + (size_t)row * 2048)[tid] = o1;
  reinterpret_cast<ushort4*>(out + (size_t)row * 2048 + 1024)[tid] = o2;
}

extern "C" void kernel_launch(void* const* d_in, const int* in_sizes, int n_in,
                              void* d_out, int out_size, void* d_ws, size_t ws_size,
                              hipStream_t stream) {
  const float* u       = (const float*)d_in[0];
  const float* W_in    = (const float*)d_in[1];
  const float* xconv_w = (const float*)d_in[2];
  const float* xconv_b = (const float*)d_in[3];
  const float* zconv_w = (const float*)d_in[4];
  const float* zconv_b = (const float*)d_in[5];
  const float* dt_bias = (const float*)d_in[6];
  const float* Alog    = (const float*)d_in[7];
  const float* Dp      = (const float*)d_in[8];
  const float* norm_w  = (const float*)d_in[9];
  const float* W_out   = (const float*)d_in[10];
  float* out = (float*)d_out;

  char* ws = (char*)d_ws;
  size_t o = 0;
  auto alc = [&](size_t bytes) { void* p = (void*)(ws + o); o = (o + bytes + 255) & ~(size_t)255; return p; };
  char* regA = (char*)alc(16777216);    // A1 (u bf16) -> yb (bf16)
  unsigned short* Wt1    = (unsigned short*)alc(4718592);   // W_in^T padded (2304 x 1024)
  unsigned short* Wt2    = (unsigned short*)alc(4194304);   // W_out^T (1024 x 2048)
  char* regZ = (char*)alc(37748736);    // zx (bf16 8192x2304) -> ypart (bf16, zx dead after convs)
  float*          dtv    = (float*)alc(262144);
  float*          csb    = (float*)alc(262144);
  unsigned short* xBC    = (unsigned short*)alc(18874368);  // 8192x1152 bf16
  unsigned short* zc     = (unsigned short*)alc(16777216);  // 8192x1024 bf16
  char* regS = (char*)alc(33554432);    // stat (bf16) -> normed (bf16 8192x2048)
  unsigned short* prevb  = (unsigned short*)alc(16777216);
  float*          Wdt    = (float*)alc(32768);              // 8 x 1024 fp32
  (void)ws_size; (void)in_sizes; (void)n_in; (void)out_size;

  unsigned short* A1     = (unsigned short*)regA;
  unsigned short* yb     = (unsigned short*)regA;
  unsigned short* zx     = (unsigned short*)regZ;
  unsigned short* ypart  = (unsigned short*)regZ;   // reuses zx region after convs consume it
  unsigned short* stat   = (unsigned short*)regS;
  unsigned short* normed = (unsigned short*)regS;

  dim3 tb(32, 8);
  wdt_kernel<<<4, 256, 0, stream>>>(W_in, Wdt);
  uin_kernel<<<2048, 256, 0, stream>>>(u, Wdt, dt_bias, A1, dtv);
  transpose_bf16_kernel<<<dim3(72, 32), tb, 0, stream>>>(W_in, Wt1, 1024, 2176, 2184);
  transpose_bf16_kernel<<<dim3(32, 64), tb, 0, stream>>>(W_out, Wt2, 2048, 1024, 1024);
  gemm_tb_kernel<1><<<576, 512, 0, stream>>>(A1, Wt1, (void*)zx, 1024, 2304, 64);
  conv_silu_tile_kernel<1152, 2304><<<576, 256, 0, stream>>>(zx + 1024, xconv_w, xconv_b, xBC);
  conv_silu_tile_kernel<1024, 2304><<<512, 256, 0, stream>>>(zx, zconv_w, zconv_b, zc);
  ssd1_kernel<<<1024, 256, 0, stream>>>(xBC, dtv, Alog, csb, stat, ypart);
  scan_kernel<<<512, 256, 0, stream>>>(stat, csb, prevb);
  ssd2_kernel<<<1024, 256, 0, stream>>>(xBC, csb, prevb, Dp, ypart, yb);
  rmsnorm_kernel<<<8192, 256, 0, stream>>>(yb, zc, norm_w, normed);
  gemm_tb_kernel<0><<<256, 512, 0, stream>>>(normed, Wt2, (void*)out, 2048, 1024, 64);
}

// Round 18
// 219.391 us; speedup vs baseline: 1.0490x; 1.0126x over previous
//
#include <hip/hip_runtime.h>
#include <stdint.h>

#define DEV __device__ __forceinline__

typedef __attribute__((ext_vector_type(8))) short bf16x8_t;   // 8 bf16 in 4 VGPRs
typedef __attribute__((ext_vector_type(4))) float f32x4_t;

DEV unsigned short f2bf(float f) {
  union { float f; uint32_t u; } x; x.f = f;
  uint32_t r = x.u + 0x7fffu + ((x.u >> 16) & 1u);
  return (unsigned short)(r >> 16);
}
DEV float bf2f(unsigned short u) {
  union { uint32_t u; float f; } x; x.u = ((uint32_t)u) << 16;
  return x.f;
}

#define GLOAD_LDS16(g, l)                                                              \
  __builtin_amdgcn_global_load_lds((const __attribute__((address_space(1))) unsigned int*)(g), \
                                   (__attribute__((address_space(3))) unsigned int*)(l), 16, 0, 0)

// ---------------- one-time gather: Wdt[h][k] = W_in[k][2176+h] ----------------
__global__ __launch_bounds__(256) void wdt_kernel(const float* __restrict__ W_in, float* __restrict__ Wdt) {
  int k = blockIdx.x * 256 + threadIdx.x;
  if (k < 1024) {
#pragma unroll
    for (int h = 0; h < 8; ++h)
      Wdt[h * 1024 + k] = W_in[(size_t)k * 2184 + 2176 + h];
  }
}

// ---------------- fused: u -> bf16 copy + dt = softplus(u @ Wdt^T + dt_bias), 4 rows/block ----------------
__global__ __launch_bounds__(256) void uin_kernel(const float* __restrict__ u, const float* __restrict__ Wdt,
                                                  const float* __restrict__ dt_bias,
                                                  unsigned short* __restrict__ A1, float* __restrict__ dtv) {
  int tid = threadIdx.x;
  int row0 = blockIdx.x * 4;
  int lane = tid & 63, wv = tid >> 6;
  float4 w4[8];
#pragma unroll
  for (int h = 0; h < 8; ++h) w4[h] = reinterpret_cast<const float4*>(Wdt + h * 1024)[tid];
  __shared__ float red[4][8];
#pragma unroll
  for (int r = 0; r < 4; ++r) {
    int row = row0 + r;
    float4 v = reinterpret_cast<const float4*>(u + (size_t)row * 1024)[tid];
    ushort4 o;
    o.x = f2bf(v.x); o.y = f2bf(v.y); o.z = f2bf(v.z); o.w = f2bf(v.w);
    reinterpret_cast<ushort4*>(A1 + (size_t)row * 1024)[tid] = o;
    float ps[8];
#pragma unroll
    for (int h = 0; h < 8; ++h)
      ps[h] = v.x * w4[h].x + v.y * w4[h].y + v.z * w4[h].z + v.w * w4[h].w;
#pragma unroll
    for (int h = 0; h < 8; ++h)
#pragma unroll
      for (int off = 32; off > 0; off >>= 1) ps[h] += __shfl_down(ps[h], off, 64);
    if (lane == 0) {
#pragma unroll
      for (int h = 0; h < 8; ++h) red[wv][h] = ps[h];
    }
    __syncthreads();
    if (tid < 8) {
      float s = red[0][tid] + red[1][tid] + red[2][tid] + red[3][tid] + dt_bias[tid];
      float sp = (s > 20.f) ? s : log1pf(expf(s));
      dtv[(size_t)row * 8 + tid] = sp;
    }
    __syncthreads();
  }
}

// ---------------- transpose fp32 (R x Cin, row stride) -> bf16 (C x R), zero-pad ----------------
__global__ void transpose_bf16_kernel(const float* __restrict__ in, unsigned short* __restrict__ out,
                                      int R, int Cin, int stride) {
  __shared__ float t[32][33];
  int bx = blockIdx.x, by = blockIdx.y;
  int tx = threadIdx.x, ty = threadIdx.y;
#pragma unroll
  for (int q = 0; q < 4; ++q) {
    int r = by * 32 + ty + q * 8, c = bx * 32 + tx;
    t[ty + q * 8][tx] = (c < Cin) ? in[(size_t)r * stride + c] : 0.f;
  }
  __syncthreads();
#pragma unroll
  for (int q = 0; q < 4; ++q) {
    int oc = bx * 32 + ty + q * 8;
    int orr = by * 32 + tx;
    out[(size_t)oc * R + orr] = f2bf(t[tx][ty + q * 8]);
  }
}

// ======== 128x256 MFMA GEMM, BK=32, counted-vmcnt N-buffer pipeline, 8 waves ========
// Chunk-XOR (round-8-verified): slot s of row r holds k-chunk (s ^ ((r>>1)&3)); staging lane-monotonic.
// Per K-step t: barrier1 -> STAGE(t+NBUF-1) -> vmcnt(3*ahead) -> barrier2 -> 12 ds_read + 16 MFMA.
// Race-free: write-target buffer was last read at t-1; each wave's ds_reads are consumed (lgkmcnt
// before MFMA) before it reaches barrier1 of t, so barrier1 certifies the buffer is free.
template <int OBF, int NBUF>
__global__ __launch_bounds__(512) void gemm_tb_kernel(const unsigned short* __restrict__ A,
                                                      const unsigned short* __restrict__ Bt,
                                                      void* __restrict__ Cout, int K, int ldc, int gx) {
  __shared__ __align__(16) char lds[NBUF * 24576];
  int tid = threadIdx.x, lane = tid & 63, wv = tid >> 6;
  int lr = lane & 15, lk = lane >> 4;
  int wm = wv >> 2, wn = wv & 3;

  int nwg = gridDim.x, lin = blockIdx.x, wg = lin;
  if ((nwg & 7) == 0) { int cpx = nwg >> 3; wg = (lin & 7) * cpx + (lin >> 3); }
  long tileM = (long)(wg % gx) * 128;
  long tileN = (long)(wg / gx) * 256;

  const unsigned short* gAp;
  {
    int q = tid, row = q >> 2, c = (q & 3) ^ ((row >> 1) & 3);
    gAp = A + (size_t)(tileM + row) * K + c * 8;
  }
  const unsigned short* gBp[2];
#pragma unroll
  for (int i = 0; i < 2; ++i) {
    int q = tid + i * 512, row = q >> 2, c = (q & 3) ^ ((row >> 1) & 3);
    gBp[i] = Bt + (size_t)(tileN + row) * K + c * 8;
  }

#define STAGE_TB(bsel, kof)                                                                  \
  do {                                                                                       \
    GLOAD_LDS16(gAp + (kof), lds + (bsel) * 24576 + tid * 16);                               \
    _Pragma("unroll") for (int i_ = 0; i_ < 2; ++i_)                                         \
        GLOAD_LDS16(gBp[i_] + (kof), lds + (bsel) * 24576 + 8192 + (tid + i_ * 512) * 16);   \
  } while (0)

  f32x4_t acc[4][4];
#pragma unroll
  for (int i = 0; i < 4; ++i)
#pragma unroll
    for (int j = 0; j < 4; ++j) acc[i][j] = f32x4_t{0.f, 0.f, 0.f, 0.f};

  int NT = K >> 5;
#pragma unroll
  for (int i = 0; i < NBUF - 1; ++i) STAGE_TB(i, i * 32);   // prologue: tiles 0..NBUF-2

  int colsw = ((lk ^ ((lr >> 1) & 3)) << 4);
  int rsel = 0, wsel = NBUF - 1;
  for (int t = 0; t < NT; ++t) {
    __builtin_amdgcn_s_barrier();
    int ahead = NT - 1 - t; if (ahead > NBUF - 1) ahead = NBUF - 1;
    if (t + NBUF - 1 < NT) STAGE_TB(wsel, (t + NBUF - 1) * 32);
    if (ahead >= 4)      asm volatile("s_waitcnt vmcnt(12)" ::: "memory");
    else if (ahead == 3) asm volatile("s_waitcnt vmcnt(9)" ::: "memory");
    else if (ahead == 2) asm volatile("s_waitcnt vmcnt(6)" ::: "memory");
    else if (ahead == 1) asm volatile("s_waitcnt vmcnt(3)" ::: "memory");
    else                 asm volatile("s_waitcnt vmcnt(0)" ::: "memory");
    __builtin_amdgcn_s_barrier();

    const char* base = lds + rsel * 24576;
    bf16x8_t a[4], b[4];
#pragma unroll
    for (int mf = 0; mf < 4; ++mf)
      a[mf] = *reinterpret_cast<const bf16x8_t*>(base + (wm * 64 + mf * 16 + lr) * 64 + colsw);
#pragma unroll
    for (int nf = 0; nf < 4; ++nf)
      b[nf] = *reinterpret_cast<const bf16x8_t*>(base + 8192 + (wn * 64 + nf * 16 + lr) * 64 + colsw);
    __builtin_amdgcn_s_setprio(1);
#pragma unroll
    for (int mf = 0; mf < 4; ++mf)
#pragma unroll
      for (int nf = 0; nf < 4; ++nf)
        acc[mf][nf] = __builtin_amdgcn_mfma_f32_16x16x32_bf16(a[mf], b[nf], acc[mf][nf], 0, 0, 0);
    __builtin_amdgcn_s_setprio(0);
    rsel = (rsel == NBUF - 1) ? 0 : rsel + 1;
    wsel = (wsel == NBUF - 1) ? 0 : wsel + 1;
  }
#undef STAGE_TB

#pragma unroll
  for (int mf = 0; mf < 4; ++mf)
#pragma unroll
    for (int nf = 0; nf < 4; ++nf) {
      long r0 = tileM + wm * 64 + mf * 16 + lk * 4;
      long c0 = tileN + wn * 64 + nf * 16 + lr;
#pragma unroll
      for (int r = 0; r < 4; ++r) {
        if (OBF)
          ((unsigned short*)Cout)[(size_t)(r0 + r) * ldc + c0] = f2bf(acc[mf][nf][r]);
        else
          ((float*)Cout)[(size_t)(r0 + r) * ldc + c0] = acc[mf][nf][r];
      }
    }
}

// ---------------- causal dwconv(4)+SiLU body, register-tiled: 8 t x 8 ch per thread ----------------
template <int C, int IN_STRIDE>
DEV void conv_body(const unsigned short* __restrict__ in, const float* __restrict__ w,
                   const float* __restrict__ bias, unsigned short* __restrict__ outp, int idx) {
  constexpr int CG = C / 8;
  int ch_grp = idx % CG;
  int tb = idx / CG;
  int t0 = (tb & 511) * 8;
  int b = tb >> 9;
  int ch0 = ch_grp * 8;

  float4 wv[8];
#pragma unroll
  for (int e = 0; e < 8; ++e) wv[e] = *reinterpret_cast<const float4*>(w + (ch0 + e) * 4);
  float bs[8];
  {
    float4 b0 = *reinterpret_cast<const float4*>(bias + ch0);
    float4 b1 = *reinterpret_cast<const float4*>(bias + ch0 + 4);
    bs[0] = b0.x; bs[1] = b0.y; bs[2] = b0.z; bs[3] = b0.w;
    bs[4] = b1.x; bs[5] = b1.y; bs[6] = b1.z; bs[7] = b1.w;
  }

  float rows[11][8];
#pragma unroll
  for (int k = 0; k < 11; ++k) {
    int t = t0 - 3 + k;
    if (t >= 0) {
      bf16x8_t v = *reinterpret_cast<const bf16x8_t*>(in + (size_t)((b << 12) + t) * IN_STRIDE + ch0);
#pragma unroll
      for (int e = 0; e < 8; ++e) rows[k][e] = bf2f((unsigned short)v[e]);
    } else {
#pragma unroll
      for (int e = 0; e < 8; ++e) rows[k][e] = 0.f;
    }
  }

#pragma unroll
  for (int tp = 0; tp < 8; ++tp) {
    bf16x8_t o;
#pragma unroll
    for (int e = 0; e < 8; ++e) {
      float a = bs[e] + wv[e].x * rows[tp][e] + wv[e].y * rows[tp + 1][e] +
                wv[e].z * rows[tp + 2][e] + wv[e].w * rows[tp + 3][e];
      a = a / (1.f + expf(-a));
      o[e] = (short)f2bf(a);
    }
    *reinterpret_cast<bf16x8_t*>(outp + (size_t)((b << 12) + t0 + tp) * C + ch0) = o;
  }
}

// ---------------- merged x-conv (blocks 0..575) + z-conv (blocks 576..1087) ----------------
__global__ __launch_bounds__(256) void conv_both_kernel(const unsigned short* __restrict__ zx,
                                                        const float* __restrict__ xw, const float* __restrict__ xb,
                                                        unsigned short* __restrict__ xBC,
                                                        const float* __restrict__ zw, const float* __restrict__ zb,
                                                        unsigned short* __restrict__ zc) {
  int blk = blockIdx.x;
  if (blk < 576) {
    conv_body<1152, 2304>(zx + 1024, xw, xb, xBC, blk * 256 + threadIdx.x);
  } else {
    conv_body<1024, 2304>(zx, zw, zb, zc, (blk - 576) * 256 + threadIdx.x);
  }
}

// ---------------- SSD pass 1 (chunk=64): cumsum + S + Y_diag + chunk states ----------------
__global__ __launch_bounds__(256) void ssd1_kernel(const unsigned short* __restrict__ xBC,
                                                   const float* __restrict__ dtv,
                                                   const float* __restrict__ Alog,
                                                   float* __restrict__ csb,
                                                   unsigned short* __restrict__ stat,
                                                   unsigned short* __restrict__ ypart) {
  int blk = blockIdx.x;
  int h = blk & 7, bc = blk >> 3;
  int c = bc & 63, b = bc >> 6;
  int tid = threadIdx.x, lane = tid & 63, wv = tid >> 6;
  int lr = lane & 15, lk = lane >> 4;
  int base = b * 4096 + c * 64;

  __shared__ float csc[64], dts[64], ew[64];
  __shared__ __align__(16) unsigned short Xd[128 * 72];
  __shared__ __align__(16) unsigned short Bnj[64 * 72];
  __shared__ __align__(16) unsigned short Ss[64 * 72];

  if (wv == 0) {
    int j = lane;
    float dt = dtv[(size_t)(base + j) * 8 + h];
    float A = -expf(Alog[h]);
    float s = dt * A;
#pragma unroll
    for (int off = 1; off < 64; off <<= 1) {
      float v = __shfl_up(s, off, 64);
      if (lane >= off) s += v;
    }
    float csl = __shfl(s, 63, 64);
    csc[j] = s; dts[j] = dt; ew[j] = expf(csl - s);
    csb[(size_t)blk * 64 + j] = s;
  }
  __syncthreads();

#pragma unroll
  for (int rr = 0; rr < 4; ++rr) {
    int j = rr * 16 + (tid >> 4);
    int pc = tid & 15;
    bf16x8_t v = *reinterpret_cast<const bf16x8_t*>(xBC + (size_t)(base + j) * 1152 + h * 128 + pc * 8);
    float dj = dts[j];
    int js = j ^ ((pc & 7) << 3);
#pragma unroll
    for (int e = 0; e < 8; ++e) {
      int p = pc * 8 + e;
      Xd[p * 72 + js] = f2bf(bf2f((unsigned short)v[e]) * dj);
    }
  }
#pragma unroll
  for (int rr = 0; rr < 2; ++rr) {
    int j = rr * 32 + (tid >> 3);
    int nc = tid & 7;
    bf16x8_t v = *reinterpret_cast<const bf16x8_t*>(xBC + (size_t)(base + j) * 1152 + 1024 + nc * 8);
    int js = j ^ ((nc & 7) << 3);
#pragma unroll
    for (int e = 0; e < 8; ++e) {
      int n = nc * 8 + e;
      Bnj[n * 72 + js] = (unsigned short)v[e];
    }
  }

  bf16x8_t cf[2];
  {
    size_t crow = (size_t)(base + wv * 16 + lr) * 1152 + 1088;
    cf[0] = *reinterpret_cast<const bf16x8_t*>(xBC + crow + lk * 8);
    cf[1] = *reinterpret_cast<const bf16x8_t*>(xBC + crow + 32 + lk * 8);
  }
  f32x4_t sacc[4];
#pragma unroll
  for (int jf = 0; jf < 4; ++jf) sacc[jf] = f32x4_t{0.f, 0.f, 0.f, 0.f};
#pragma unroll
  for (int ks = 0; ks < 2; ++ks) {
#pragma unroll
    for (int jf = 0; jf < 4; ++jf) {
      bf16x8_t bv = *reinterpret_cast<const bf16x8_t*>(
          xBC + (size_t)(base + jf * 16 + lr) * 1152 + 1024 + ks * 32 + lk * 8);
      sacc[jf] = __builtin_amdgcn_mfma_f32_16x16x32_bf16(cf[ks], bv, sacc[jf], 0, 0, 0);
    }
  }
  __syncthreads();

  {
    float csi[4];
#pragma unroll
    for (int r = 0; r < 4; ++r) csi[r] = csc[wv * 16 + lk * 4 + r];
#pragma unroll
    for (int jf = 0; jf < 4; ++jf) {
      int j = jf * 16 + lr;
      float csj = csc[j];
#pragma unroll
      for (int r = 0; r < 4; ++r) {
        int i = wv * 16 + lk * 4 + r;
        float w = (j <= i) ? expf(csi[r] - csj) : 0.f;
        Ss[i * 72 + j] = f2bf(sacc[jf][r] * w);
      }
    }
  }
  __syncthreads();

  f32x4_t yacc[8];
#pragma unroll
  for (int pf = 0; pf < 8; ++pf) yacc[pf] = f32x4_t{0.f, 0.f, 0.f, 0.f};
  bf16x8_t sa[2];
  sa[0] = *reinterpret_cast<const bf16x8_t*>(Ss + (wv * 16 + lr) * 72 + lk * 8);
  sa[1] = *reinterpret_cast<const bf16x8_t*>(Ss + (wv * 16 + lr) * 72 + 32 + lk * 8);
#pragma unroll
  for (int ks = 0; ks < 2; ++ks) {
    int jb = ks * 32 + lk * 8;
#pragma unroll
    for (int pf = 0; pf < 8; ++pf) {
      int p = pf * 16 + lr;
      bf16x8_t xv = *reinterpret_cast<const bf16x8_t*>(Xd + p * 72 + (jb ^ (((p >> 3) & 7) << 3)));
      yacc[pf] = __builtin_amdgcn_mfma_f32_16x16x32_bf16(sa[ks], xv, yacc[pf], 0, 0, 0);
    }
  }

  f32x4_t st[2][4];
#pragma unroll
  for (int pb = 0; pb < 2; ++pb)
#pragma unroll
    for (int nf = 0; nf < 4; ++nf) st[pb][nf] = f32x4_t{0.f, 0.f, 0.f, 0.f};
#pragma unroll
  for (int pb = 0; pb < 2; ++pb) {
    int p = wv * 32 + pb * 16 + lr;
#pragma unroll
    for (int ks = 0; ks < 2; ++ks) {
      int jb = ks * 32 + lk * 8;
      bf16x8_t xv = *reinterpret_cast<const bf16x8_t*>(Xd + p * 72 + (jb ^ (((p >> 3) & 7) << 3)));
      bf16x8_t xs;
#pragma unroll
      for (int e = 0; e < 8; ++e) xs[e] = (short)f2bf(bf2f((unsigned short)xv[e]) * ew[jb + e]);
#pragma unroll
      for (int nf = 0; nf < 4; ++nf) {
        int n = nf * 16 + lr;
        bf16x8_t bv = *reinterpret_cast<const bf16x8_t*>(Bnj + n * 72 + (jb ^ (((n >> 3) & 7) << 3)));
        st[pb][nf] = __builtin_amdgcn_mfma_f32_16x16x32_bf16(xs, bv, st[pb][nf], 0, 0, 0);
      }
    }
  }

#pragma unroll
  for (int pf = 0; pf < 8; ++pf)
#pragma unroll
    for (int r = 0; r < 4; ++r) {
      int i = wv * 16 + lk * 4 + r;
      ypart[(size_t)(base + i) * 1024 + h * 128 + pf * 16 + lr] = f2bf(yacc[pf][r]);
    }
  unsigned short* so = stat + (size_t)blk * 8192;
#pragma unroll
  for (int pb = 0; pb < 2; ++pb)
#pragma unroll
    for (int nf = 0; nf < 4; ++nf)
#pragma unroll
      for (int r = 0; r < 4; ++r)
        so[(size_t)(wv * 32 + pb * 16 + lk * 4 + r) * 64 + nf * 16 + lr] = f2bf(st[pb][nf][r]);
}

// ---------------- element-parallel inter-chunk scan (64 chunks), prev -> bf16 ----------------
__global__ __launch_bounds__(256) void scan_kernel(const unsigned short* __restrict__ stat,
                                                   const float* __restrict__ csb,
                                                   unsigned short* __restrict__ prevb) {
  int bh = blockIdx.x >> 5;
  int part = blockIdx.x & 31;
  int h = bh & 7, b = bh >> 3;
  int e = part * 256 + threadIdx.x;
  float carry = 0.f;
  for (int c = 0; c < 64; ++c) {
    size_t blk = (size_t)(b * 64 + c) * 8 + h;
    size_t idx = blk * 8192 + e;
    prevb[idx] = f2bf(carry);
    float dec = expf(csb[blk * 64 + 63]);
    carry = bf2f(stat[idx]) + dec * carry;
  }
}

// ---------------- SSD pass 2: Y = ypart + (C e^cs) @ prev^T + D x ----------------
__global__ __launch_bounds__(256) void ssd2_kernel(const unsigned short* __restrict__ xBC,
                                                   const float* __restrict__ csb,
                                                   const unsigned short* __restrict__ prevb,
                                                   const float* __restrict__ Dp,
                                                   const unsigned short* __restrict__ ypart,
                                                   unsigned short* __restrict__ yb) {
  int blk = blockIdx.x;
  int h = blk & 7, bc = blk >> 3;
  int c = bc & 63, b = bc >> 6;
  int tid = threadIdx.x, lane = tid & 63, wv = tid >> 6;
  int lr = lane & 15, lk = lane >> 4;
  int base = b * 4096 + c * 64;
  __shared__ float csc[64];
  if (tid < 64) csc[tid] = csb[(size_t)blk * 64 + tid];
  __syncthreads();

  float sc = expf(csc[wv * 16 + lr]);
  bf16x8_t ca[2];
  {
    size_t crow = (size_t)(base + wv * 16 + lr) * 1152 + 1088;
#pragma unroll
    for (int ks = 0; ks < 2; ++ks) {
      bf16x8_t v = *reinterpret_cast<const bf16x8_t*>(xBC + crow + ks * 32 + lk * 8);
      bf16x8_t d;
#pragma unroll
      for (int e = 0; e < 8; ++e) d[e] = (short)f2bf(bf2f((unsigned short)v[e]) * sc);
      ca[ks] = d;
    }
  }
  f32x4_t acc[8];
#pragma unroll
  for (int pf = 0; pf < 8; ++pf) acc[pf] = f32x4_t{0.f, 0.f, 0.f, 0.f};
#pragma unroll
  for (int ks = 0; ks < 2; ++ks) {
#pragma unroll
    for (int pf = 0; pf < 8; ++pf) {
      bf16x8_t pv = *reinterpret_cast<const bf16x8_t*>(
          prevb + (size_t)blk * 8192 + (size_t)(pf * 16 + lr) * 64 + ks * 32 + lk * 8);
      acc[pf] = __builtin_amdgcn_mfma_f32_16x16x32_bf16(ca[ks], pv, acc[pf], 0, 0, 0);
    }
  }
  float Dh = Dp[h];
#pragma unroll
  for (int pf = 0; pf < 8; ++pf)
#pragma unroll
    for (int r = 0; r < 4; ++r) {
      int i = wv * 16 + lk * 4 + r;
      size_t row = (size_t)(base + i);
      int p = pf * 16 + lr;
      float xr = bf2f(xBC[row * 1152 + h * 128 + p]);
      float yv = bf2f(ypart[row * 1024 + h * 128 + p]) + acc[pf][r] + Dh * xr;
      yb[row * 1024 + h * 128 + p] = f2bf(yv);
    }
}

// ---------------- RMSNorm over concat(y, z) bf16 -> bf16 ----------------
__global__ __launch_bounds__(256) void rmsnorm_kernel(const unsigned short* __restrict__ y,
                                                      const unsigned short* __restrict__ z,
                                                      const float* __restrict__ nw,
                                                      unsigned short* __restrict__ out) {
  int row = blockIdx.x, tid = threadIdx.x;
  ushort4 ya = reinterpret_cast<const ushort4*>(y + (size_t)row * 1024)[tid];
  ushort4 za = reinterpret_cast<const ushort4*>(z + (size_t)row * 1024)[tid];
  float yf[4] = {bf2f(ya.x), bf2f(ya.y), bf2f(ya.z), bf2f(ya.w)};
  float zf[4] = {bf2f(za.x), bf2f(za.y), bf2f(za.z), bf2f(za.w)};
  float ss = yf[0] * yf[0] + yf[1] * yf[1] + yf[2] * yf[2] + yf[3] * yf[3] +
             zf[0] * zf[0] + zf[1] * zf[1] + zf[2] * zf[2] + zf[3] * zf[3];
#pragma unroll
  for (int off = 32; off > 0; off >>= 1) ss += __shfl_down(ss, off, 64);
  __shared__ float red[4];
  __shared__ float stot;
  int lane = tid & 63, wv = tid >> 6;
  if (lane == 0) red[wv] = ss;
  __syncthreads();
  if (tid == 0) stot = rsqrtf((red[0] + red[1] + red[2] + red[3]) * (1.f / 2048.f) + 1e-5f);
  __syncthreads();
  float s = stot;
  float4 w1 = reinterpret_cast<const float4*>(nw)[tid];
  float4 w2 = reinterpret_cast<const float4*>(nw + 1024)[tid];
  ushort4 o1, o2;
  o1.x = f2bf(yf[0] * s * w1.x); o1.y = f2bf(yf[1] * s * w1.y);
  o1.z = f2bf(yf[2] * s * w1.z); o1.w = f2bf(yf[3] * s * w1.w);
  o2.x = f2bf(zf[0] * s * w2.x); o2.y = f2bf(zf[1] * s * w2.y);
  o2.z = f2bf(zf[2] * s * w2.z); o2.w = f2bf(zf[3] * s * w2.w);
  reinterpret_cast<ushort4*>(out + (size_t)row * 2048)[tid] = o1;
  reinterpret_cast<ushort4*>(out + (size_t)row * 2048 + 1024)[tid] = o2;
}

extern "C" void kernel_launch(void* const* d_in, const int* in_sizes, int n_in,
                              void* d_out, int out_size, void* d_ws, size_t ws_size,
                              hipStream_t stream) {
  const float* u       = (const float*)d_in[0];
  const float* W_in    = (const float*)d_in[1];
  const float* xconv_w = (const float*)d_in[2];
  const float* xconv_b = (const float*)d_in[3];
  const float* zconv_w = (const float*)d_in[4];
  const float* zconv_b = (const float*)d_in[5];
  const float* dt_bias = (const float*)d_in[6];
  const float* Alog    = (const float*)d_in[7];
  const float* Dp      = (const float*)d_in[8];
  const float* norm_w  = (const float*)d_in[9];
  const float* W_out   = (const float*)d_in[10];
  float* out = (float*)d_out;

  char* ws = (char*)d_ws;
  size_t o = 0;
  auto alc = [&](size_t bytes) { void* p = (void*)(ws + o); o = (o + bytes + 255) & ~(size_t)255; return p; };
  char* regA = (char*)alc(16777216);    // A1 (u bf16) -> yb (bf16)
  unsigned short* Wt1    = (unsigned short*)alc(4718592);   // W_in^T padded (2304 x 1024)
  unsigned short* Wt2    = (unsigned short*)alc(4194304);   // W_out^T (1024 x 2048)
  char* regZ = (char*)alc(37748736);    // zx (bf16 8192x2304) -> ypart (bf16, zx dead after convs)
  float*          dtv    = (float*)alc(262144);
  float*          csb    = (float*)alc(262144);
  unsigned short* xBC    = (unsigned short*)alc(18874368);  // 8192x1152 bf16
  unsigned short* zc     = (unsigned short*)alc(16777216);  // 8192x1024 bf16
  char* regS = (char*)alc(33554432);    // stat (bf16) -> normed (bf16 8192x2048)
  unsigned short* prevb  = (unsigned short*)alc(16777216);
  float*          Wdt    = (float*)alc(32768);              // 8 x 1024 fp32
  (void)ws_size; (void)in_sizes; (void)n_in; (void)out_size;

  unsigned short* A1     = (unsigned short*)regA;
  unsigned short* yb     = (unsigned short*)regA;
  unsigned short* zx     = (unsigned short*)regZ;
  unsigned short* ypart  = (unsigned short*)regZ;   // reuses zx region after convs consume it
  unsigned short* stat   = (unsigned short*)regS;
  unsigned short* normed = (unsigned short*)regS;

  dim3 tb(32, 8);
  wdt_kernel<<<4, 256, 0, stream>>>(W_in, Wdt);
  uin_kernel<<<2048, 256, 0, stream>>>(u, Wdt, dt_bias, A1, dtv);
  transpose_bf16_kernel<<<dim3(72, 32), tb, 0, stream>>>(W_in, Wt1, 1024, 2176, 2184);
  transpose_bf16_kernel<<<dim3(32, 64), tb, 0, stream>>>(W_out, Wt2, 2048, 1024, 1024);
  gemm_tb_kernel<1, 3><<<576, 512, 0, stream>>>(A1, Wt1, (void*)zx, 1024, 2304, 64);
  conv_both_kernel<<<1088, 256, 0, stream>>>(zx, xconv_w, xconv_b, xBC, zconv_w, zconv_b, zc);
  ssd1_kernel<<<1024, 256, 0, stream>>>(xBC, dtv, Alog, csb, stat, ypart);
  scan_kernel<<<512, 256, 0, stream>>>(stat, csb, prevb);
  ssd2_kernel<<<1024, 256, 0, stream>>>(xBC, csb, prevb, Dp, ypart, yb);
  rmsnorm_kernel<<<8192, 256, 0, stream>>>(yb, zc, norm_w, normed);
  gemm_tb_kernel<0, 5><<<256, 512, 0, stream>>>(normed, Wt2, (void*)out, 2048, 1024, 64);
}